// Round 2
// baseline (858.637 us; speedup 1.0000x reference)
//
#include <hip/hip_runtime.h>
#include <cstddef>

#define H 128

typedef unsigned short ushort_t;
typedef unsigned char uchar_t;
typedef __attribute__((ext_vector_type(8))) short short8;
typedef __attribute__((ext_vector_type(4))) float floatx4;
typedef __attribute__((ext_vector_type(2))) float floatx2;

// ---------------- helpers ----------------
__device__ __forceinline__ unsigned fkey(float f){
    unsigned u = __float_as_uint(f);
    return (u & 0x80000000u) ? ~u : (u | 0x80000000u);
}
__device__ __forceinline__ float funkey(unsigned k){
    unsigned u = (k & 0x80000000u) ? (k ^ 0x80000000u) : ~k;
    return __uint_as_float(u);
}
__device__ __forceinline__ ushort_t f2bf(float f){
    unsigned u = __float_as_uint(f);
    u += 0x7fffu + ((u >> 16) & 1u);      // round-to-nearest-even
    return (ushort_t)(u >> 16);
}
__device__ __forceinline__ float bf2f(ushort_t h){
    return __uint_as_float(((unsigned)h) << 16);
}
__device__ __forceinline__ uchar_t f2fp8(float v){
    int p = __builtin_amdgcn_cvt_pk_fp8_f32(v, v, 0, false);
    return (uchar_t)(p & 0xff);
}
// async global -> LDS, 16B per lane. LDS dest = wave-uniform base + lane*16.
__device__ __forceinline__ void gll16(const void* g, void* l){
    __builtin_amdgcn_global_load_lds(
        (const __attribute__((address_space(1))) unsigned int*)g,
        (__attribute__((address_space(3))) unsigned int*)l, 16, 0, 0);
}

// ---------------- embeddings (write bf16 states) ----------------
__global__ __launch_bounds__(256) void k_embed_place(
    const float* __restrict__ pf, const float* __restrict__ Wpe,
    const float* __restrict__ bpe, ushort_t* __restrict__ out, int P)
{
    int idx = blockIdx.x*256 + threadIdx.x;     // 4-elem group index over P*32
    if (idx >= P*32) return;
    int p = idx >> 5, q = (idx & 31) << 2;
    float v = pf[p];
    float4 w = *(const float4*)(Wpe + q);
    float4 b = *(const float4*)(bpe + q);
    ushort4 o;
    o.x = f2bf(v*w.x + b.x); o.y = f2bf(v*w.y + b.y);
    o.z = f2bf(v*w.z + b.z); o.w = f2bf(v*w.w + b.w);
    *(ushort4*)(out + (size_t)p*H + q) = o;
}

__global__ __launch_bounds__(256) void k_embed_trans(
    const float* __restrict__ tf, const float* __restrict__ Wte,
    const float* __restrict__ bte, ushort_t* __restrict__ out, int T)
{
    __shared__ float Wl[8*H];
    __shared__ float Bl[H];
    int tid = threadIdx.x;
    #pragma unroll
    for (int t = 0; t < 4; t++) Wl[tid + t*256] = Wte[tid + t*256];
    if (tid < H) Bl[tid] = bte[tid];
    __syncthreads();
    int idx = blockIdx.x*256 + tid;
    if (idx >= T*32) return;
    int t = idx >> 5, q = (idx & 31) << 2;
    float4 acc = *(float4*)(&Bl[q]);
    #pragma unroll
    for (int k = 0; k < 8; k++){
        float s = tf[(size_t)t*8 + k];
        float4 w = *(float4*)(&Wl[k*H + q]);
        acc.x += s*w.x; acc.y += s*w.y; acc.z += s*w.z; acc.w += s*w.w;
    }
    ushort4 o;
    o.x = f2bf(acc.x); o.y = f2bf(acc.y); o.z = f2bf(acc.z); o.w = f2bf(acc.w);
    *(ushort4*)(out + (size_t)t*H + q) = o;
}

// prefix embedding + zero small accumulators + all softmax slots
__global__ void k_init_small(const float* __restrict__ pe, int plen,
                             const float* __restrict__ Wpr, const float* __restrict__ bpr,
                             float* __restrict__ prefix, float* __restrict__ meanP,
                             float* __restrict__ meanT, float* __restrict__ slots)
{
    int c = threadIdx.x;  // 128 threads
    float a = bpr[c];
    for (int k = 0; k < plen; k++) a += pe[k]*Wpr[k*H + c];
    prefix[c] = a;
    meanP[c] = 0.f;
    meanT[c] = 0.f;
    if (c < 16) slots[c] = 0.f;   // fkey-space 0 == -inf; Sp slots start at 0
}

// ---------------- weight transpose + bf16 convert ----------------
// per layer l: WT layout [p2tT 128x128][t2pT 128x128][tuT 128x256][puT 128x256]
__global__ __launch_bounds__(256) void k_wconv(
    const float* __restrict__ p2t_W, const float* __restrict__ t2p_W,
    const float* __restrict__ tu_W,  const float* __restrict__ pu_W,
    ushort_t* __restrict__ WT, int total)
{
    int e = blockIdx.x*256 + threadIdx.x;
    if (e >= total) return;
    int l = e / 98304, o = e - l*98304;
    const float* src; int K, oo;
    if (o < 16384)      { src = p2t_W + (size_t)l*16384; K = 128; oo = o; }
    else if (o < 32768) { src = t2p_W + (size_t)l*16384; K = 128; oo = o - 16384; }
    else if (o < 65536) { src = tu_W  + (size_t)l*32768; K = 256; oo = o - 32768; }
    else                { src = pu_W  + (size_t)l*32768; K = 256; oo = o - 65536; }
    int n = oo / K, k = oo - n*K;
    WT[e] = f2bf(src[(size_t)k*H + n]);
}

// ---------------- CSR build ----------------
__global__ __launch_bounds__(256) void k_zero_ints(int* __restrict__ p, int n)
{
    int i = blockIdx.x*256 + threadIdx.x;
    int stride = gridDim.x*256;
    for (; i < n; i += stride) p[i] = 0;
}

// dst histograms + per-edge segment ranks (2 atomics/edge)
__global__ __launch_bounds__(256) void k_hist2(
    const int* __restrict__ preD, const int* __restrict__ postD, int E,
    int* __restrict__ cntPre, int* __restrict__ cntPost,
    int* __restrict__ rankPre, int* __restrict__ rankPost)
{
    int i = blockIdx.x*256 + threadIdx.x;
    int stride = gridDim.x*256;
    for (; i < E; i += stride){
        rankPre[i] = atomicAdd(&cntPre[preD[i]], 1);
        rankPost[i] = atomicAdd(&cntPost[postD[i]], 1);
    }
}

// ---- multi-block exclusive scan (chunk = 1024 per block) ----
__global__ __launch_bounds__(256) void k_scan_part(
    const int* __restrict__ cnt, int N, int* __restrict__ bsum)
{
    __shared__ int wsum[4];
    int tid = threadIdx.x, lane = tid & 63, wid = tid >> 6;
    int base = blockIdx.x*1024 + tid*4;
    int4 v = make_int4(0,0,0,0);
    if (base + 3 < N) v = *(const int4*)(cnt + base);
    else {
        if (base+0 < N) v.x = cnt[base+0];
        if (base+1 < N) v.y = cnt[base+1];
        if (base+2 < N) v.z = cnt[base+2];
    }
    int s = v.x + v.y + v.z + v.w;
    #pragma unroll
    for (int o = 1; o < 64; o <<= 1) s += __shfl_xor(s, o);
    if (lane == 0) wsum[wid] = s;
    __syncthreads();
    if (tid == 0) bsum[blockIdx.x] = wsum[0] + wsum[1] + wsum[2] + wsum[3];
}

__global__ __launch_bounds__(256) void k_scan_bsum(int* __restrict__ bsum, int nb)
{
    __shared__ int wsum[4];
    int tid = threadIdx.x, lane = tid & 63, wid = tid >> 6;
    int x = (tid < nb) ? bsum[tid] : 0;
    int inc = x;
    #pragma unroll
    for (int o = 1; o < 64; o <<= 1){
        int u = __shfl_up(inc, o);
        if (lane >= o) inc += u;
    }
    if (lane == 63) wsum[wid] = inc;
    __syncthreads();
    int woff = 0;
    if (wid > 0) woff += wsum[0];
    if (wid > 1) woff += wsum[1];
    if (wid > 2) woff += wsum[2];
    if (tid < nb) bsum[tid] = woff + inc - x;
}

__global__ __launch_bounds__(256) void k_scan_final(
    const int* __restrict__ cnt, int N, const int* __restrict__ bsum,
    int* __restrict__ rp, int E)
{
    __shared__ int wsum[4];
    int tid = threadIdx.x, lane = tid & 63, wid = tid >> 6;
    int base = blockIdx.x*1024 + tid*4;
    int4 v = make_int4(0,0,0,0);
    if (base + 3 < N) v = *(const int4*)(cnt + base);
    else {
        if (base+0 < N) v.x = cnt[base+0];
        if (base+1 < N) v.y = cnt[base+1];
        if (base+2 < N) v.z = cnt[base+2];
    }
    int t0 = v.x, t1 = t0 + v.y, t2 = t1 + v.z, t3 = t2 + v.w;
    int inc = t3;
    #pragma unroll
    for (int o = 1; o < 64; o <<= 1){
        int u = __shfl_up(inc, o);
        if (lane >= o) inc += u;
    }
    if (lane == 63) wsum[wid] = inc;
    __syncthreads();
    int woff = 0;
    if (wid > 0) woff += wsum[0];
    if (wid > 1) woff += wsum[1];
    if (wid > 2) woff += wsum[2];
    int off = bsum[blockIdx.x] + woff + inc - t3;
    if (base+0 < N) rp[base+0] = off;
    if (base+1 < N) rp[base+1] = off + t0;
    if (base+2 < N) rp[base+2] = off + t1;
    if (base+3 < N) rp[base+3] = off + t2;
    if (blockIdx.x == 0 && tid == 0) rp[N] = E;
}

// atomic-free CSR fill using precomputed ranks
__global__ __launch_bounds__(256) void k_fill2(
    const int* __restrict__ preS, const int* __restrict__ preD,
    const int* __restrict__ postS, const int* __restrict__ postD, int E,
    const int* __restrict__ rpPre, const int* __restrict__ rankPre, int* __restrict__ csrPre,
    const int* __restrict__ rpPost, const int* __restrict__ rankPost, int* __restrict__ csrPost)
{
    int i = blockIdx.x*256 + threadIdx.x;
    int stride = gridDim.x*256;
    for (; i < E; i += stride){
        csrPre[rpPre[preD[i]] + rankPre[i]] = preS[i];
        csrPost[rpPost[postD[i]] + rankPost[i]] = postS[i];
    }
}

// ---------------- message GEMM: out(fp8) = A @ W + b, partial score (K=128) --
// ALL tiles (up to 5) staged up-front via global_load_lds into 5 dedicated LDS
// buffers (no reuse, no WAR) with constant counted-vmcnt waits per tile.
// LDS XOR-swizzled via pre-swizzled global source (u ^= row&15).
// W strips in registers. REQUIRES M % 16 == 0.
__global__ __launch_bounds__(256, 4) void k_gemm_msg(
    const ushort_t* __restrict__ A, const ushort_t* __restrict__ WT,
    const float* __restrict__ bias, uchar_t* __restrict__ out, int M,
    const float* __restrict__ aw, float* __restrict__ y4)
{
    __shared__ __align__(16) char As[5*4096];   // 5 x (16 rows x 256B)
    int tid = threadIdx.x;
    int lane = tid & 63, wid = tid >> 6;
    int quad = lane >> 4, l15 = lane & 15;
    int strip = wid*32;
    short8 bfr[2][4];
    float bcol[2], awc[2];
    #pragma unroll
    for (int j = 0; j < 2; j++){
        int col = strip + j*16 + l15;
        #pragma unroll
        for (int kk = 0; kk < 4; kk++)
            bfr[j][kk] = *(const short8*)(WT + (size_t)col*128 + kk*32 + quad*8);
        bcol[j] = bias[col];
        awc[j]  = aw[col];
    }
    int tiles = (M + 15) >> 4;
    int G = gridDim.x;
    int t0 = blockIdx.x;
    if (t0 >= tiles) return;
    int nt = (tiles - t0 + G - 1)/G; if (nt > 5) nt = 5;

    // staging source: thread tid owns chunk (row=tid>>4, u=tid&15); the
    // global source u is inverse-swizzled so the linear DMA write lands
    // the swizzled layout (both-sides involution).
    int srow = tid >> 4;
    int su = (tid & 15) ^ srow;
    const ushort_t* gb = A + (size_t)srow*H + su*8;

    #pragma unroll
    for (int k = 0; k < 5; k++)
        if (k < nt)
            gll16(gb + (size_t)(t0 + k*G)*(16*H), As + k*4096 + (wid<<10));

    // per tile per wave: 8 fp8 stores + 4 y4 stores = 12 vmcnt ops
#define MSG_BODY(k)                                                            \
    {                                                                          \
        const char* rb = As + (k)*4096;                                        \
        int row0 = (t0 + (k)*G) << 4;                                          \
        short8 afr[4];                                                         \
        _Pragma("unroll")                                                      \
        for (int kk = 0; kk < 4; kk++)                                         \
            afr[kk] = *(const short8*)(rb + (l15<<8) + ((((kk<<2)+quad) ^ l15) << 4)); \
        floatx4 acc[2];                                                        \
        acc[0] = (floatx4)0.f; acc[1] = (floatx4)0.f;                          \
        _Pragma("unroll")                                                      \
        for (int j = 0; j < 2; j++)                                            \
            _Pragma("unroll")                                                  \
            for (int kk = 0; kk < 4; kk++)                                     \
                acc[j] = __builtin_amdgcn_mfma_f32_16x16x32_bf16(afr[kk], bfr[j][kk], acc[j], 0,0,0); \
        float pr[4] = {0.f,0.f,0.f,0.f};                                       \
        _Pragma("unroll")                                                      \
        for (int j = 0; j < 2; j++){                                           \
            int col = strip + j*16 + l15;                                      \
            _Pragma("unroll")                                                  \
            for (int rr = 0; rr < 4; rr++){                                    \
                int grow = row0 + quad*4 + rr;                                 \
                float v = acc[j][rr] + bcol[j];                                \
                out[(size_t)grow*H + col] = f2fp8(v);                          \
                pr[rr] += v * awc[j];                                          \
            }                                                                  \
        }                                                                      \
        _Pragma("unroll")                                                      \
        for (int rr = 0; rr < 4; rr++){                                        \
            float p = pr[rr];                                                  \
            p += __shfl_xor(p, 1); p += __shfl_xor(p, 2);                      \
            p += __shfl_xor(p, 4); p += __shfl_xor(p, 8);                      \
            int grow = row0 + quad*4 + rr;                                     \
            if (l15 == 0) y4[(size_t)grow*4 + wid] = p;                        \
        }                                                                      \
    }

    if (nt == 5){
        // wait for stage k: ops newer = (4-k) stages + 12k stores
        asm volatile("s_waitcnt vmcnt(4)\ns_barrier" ::: "memory");  MSG_BODY(0)
        asm volatile("s_waitcnt vmcnt(15)\ns_barrier" ::: "memory"); MSG_BODY(1)
        asm volatile("s_waitcnt vmcnt(26)\ns_barrier" ::: "memory"); MSG_BODY(2)
        asm volatile("s_waitcnt vmcnt(37)\ns_barrier" ::: "memory"); MSG_BODY(3)
        asm volatile("s_waitcnt vmcnt(48)\ns_barrier" ::: "memory"); MSG_BODY(4)
    } else {
        for (int k = 0; k < nt; k++){
            asm volatile("s_waitcnt vmcnt(0)\ns_barrier" ::: "memory");
            switch(k){
                case 0: MSG_BODY(0) break;
                case 1: MSG_BODY(1) break;
                case 2: MSG_BODY(2) break;
                case 3: MSG_BODY(3) break;
                default: MSG_BODY(4) break;
            }
        }
    }
#undef MSG_BODY
}

// ---------------- finalize scores: y = sum(y4) + ab; node max -> Mkey --------
__global__ __launch_bounds__(256) void k_scoremax(
    const float* __restrict__ y4, int N, const float* __restrict__ abp,
    float* __restrict__ y, unsigned* __restrict__ Mkey)
{
    __shared__ float wm[4];
    int tid = threadIdx.x;
    int lane = tid & 63, wid = tid >> 6;
    int gid = blockIdx.x*256 + tid, stride = gridDim.x*256;
    float ab = abp[0];
    float lmax = -3.402823466e38f;
    for (int r = gid; r < N; r += stride){
        float4 v = *(const float4*)(y4 + (size_t)r*4);
        float s = v.x + v.y + v.z + v.w + ab;
        y[r] = s;
        lmax = fmaxf(lmax, s);
    }
    #pragma unroll
    for (int o = 1; o < 64; o <<= 1) lmax = fmaxf(lmax, __shfl_xor(lmax, o));
    if (lane == 0) wm[wid] = lmax;
    __syncthreads();
    if (tid == 0){
        float m = fmaxf(fmaxf(wm[0], wm[1]), fmaxf(wm[2], wm[3]));
        atomicMax(Mkey, fkey(m));
    }
}

// ---------------- softmax denominator over edge src list --------------------
__global__ __launch_bounds__(256) void k_sumexp(
    const int* __restrict__ src, int E, const float* __restrict__ y,
    const unsigned* __restrict__ Mkey, float* __restrict__ Sp)
{
    __shared__ float red[4];
    int tid = threadIdx.x, lane = tid & 63, wid = tid >> 6;
    int gid = blockIdx.x*256 + tid, stride = gridDim.x*256;
    float Mv = funkey(Mkey[0]);
    float ls = 0.f;
    for (int e = gid; e < E; e += stride) ls += expf(y[src[e]] - Mv);
    #pragma unroll
    for (int o = 1; o < 64; o <<= 1) ls += __shfl_xor(ls, o);
    if (lane == 0) red[wid] = ls;
    __syncthreads();
    if (tid == 0) atomicAdd(Sp, red[0] + red[1] + red[2] + red[3]);
}

// ---------------- update GEMM: out = relu(A1 + A1@W_up + invS*(Mb@W_low) + b)
// Same all-upfront staging (5 x 8KB buffers: A1 4KB | A2 4KB each).
// Residual A1 via identity-B MFMA. csum aliased onto buffer 0 (dead by
// epilogue) to keep LDS at exactly 40960 (4 blocks/CU). REQUIRES M%16==0.
__global__ __launch_bounds__(256, 4) void k_gemm_up(
    const ushort_t* __restrict__ A1, const ushort_t* __restrict__ A2,
    const ushort_t* __restrict__ WT, const float* __restrict__ bias,
    const float* __restrict__ Sp, ushort_t* __restrict__ out, int M,
    float* __restrict__ colsum)
{
    __shared__ __align__(16) char As[5*8192];
    int tid = threadIdx.x;
    int lane = tid & 63, wid = tid >> 6;
    int quad = lane >> 4, l15 = lane & 15;
    int strip = wid*32;
    short8 bfr1[2][4], bfr2[2][4];
    float bcol[2];
    #pragma unroll
    for (int j = 0; j < 2; j++){
        int col = strip + j*16 + l15;
        #pragma unroll
        for (int kk = 0; kk < 4; kk++){
            bfr1[j][kk] = *(const short8*)(WT + (size_t)col*256 + kk*32 + quad*8);
            bfr2[j][kk] = *(const short8*)(WT + (size_t)col*256 + 128 + kk*32 + quad*8);
        }
        bcol[j] = bias[col];
    }
    // identity B-fragments: B[kloc][c] = (kloc == 16j + c); transposes the
    // wave's A1 fragment window (k in [32*wid,32*wid+32)) into C-layout.
    short8 If0, If1;
    #pragma unroll
    for (int e = 0; e < 8; e++){
        int kloc = quad*8 + e;
        If0[e] = (kloc == l15)      ? (short)0x3F80 : (short)0;
        If1[e] = (kloc == l15 + 16) ? (short)0x3F80 : (short)0;
    }
    float invS = 1.f / Sp[0];
    const bool has_cs = (colsum != nullptr);

    int tiles = (M + 15) >> 4;
    int G = gridDim.x;
    int t0 = blockIdx.x;
    if (t0 >= tiles) return;
    int nt = (tiles - t0 + G - 1)/G; if (nt > 5) nt = 5;

    int srow = tid >> 4;
    int su = (tid & 15) ^ srow;
    const ushort_t* g1b = A1 + (size_t)srow*H + su*8;
    const ushort_t* g2b = A2 + (size_t)srow*H + su*8;

    #pragma unroll
    for (int k = 0; k < 5; k++)
        if (k < nt){
            gll16(g1b + (size_t)(t0 + k*G)*(16*H), As + k*8192 + (wid<<10));
            gll16(g2b + (size_t)(t0 + k*G)*(16*H), As + k*8192 + 4096 + (wid<<10));
        }

    float cs[2] = {0.f, 0.f};
    // per tile per wave: 8 ushort stores = 8 vmcnt ops
#define UP_BODY(k)                                                             \
    {                                                                          \
        const char* rb = As + (k)*8192;                                        \
        int row0 = (t0 + (k)*G) << 4;                                          \
        short8 a1f[4], a2f[4];                                                 \
        _Pragma("unroll")                                                      \
        for (int kk = 0; kk < 4; kk++){                                        \
            int sw = ((((kk<<2)+quad) ^ l15) << 4);                            \
            a1f[kk] = *(const short8*)(rb + (l15<<8) + sw);                    \
            a2f[kk] = *(const short8*)(rb + 4096 + (l15<<8) + sw);             \
        }                                                                      \
        short8 ares = *(const short8*)(rb + (l15<<8) + ((((wid<<2)+quad) ^ l15) << 4)); \
        floatx4 acc1[2], acc2[2];                                              \
        acc1[0] = __builtin_amdgcn_mfma_f32_16x16x32_bf16(ares, If0, (floatx4)0.f, 0,0,0); \
        acc1[1] = __builtin_amdgcn_mfma_f32_16x16x32_bf16(ares, If1, (floatx4)0.f, 0,0,0); \
        acc2[0] = (floatx4)0.f; acc2[1] = (floatx4)0.f;                        \
        _Pragma("unroll")                                                      \
        for (int j = 0; j < 2; j++){                                           \
            _Pragma("unroll")                                                  \
            for (int kk = 0; kk < 4; kk++)                                     \
                acc1[j] = __builtin_amdgcn_mfma_f32_16x16x32_bf16(a1f[kk], bfr1[j][kk], acc1[j], 0,0,0); \
            _Pragma("unroll")                                                  \
            for (int kk = 0; kk < 4; kk++)                                     \
                acc2[j] = __builtin_amdgcn_mfma_f32_16x16x32_bf16(a2f[kk], bfr2[j][kk], acc2[j], 0,0,0); \
        }                                                                      \
        _Pragma("unroll")                                                      \
        for (int j = 0; j < 2; j++){                                           \
            int col = strip + j*16 + l15;                                      \
            _Pragma("unroll")                                                  \
            for (int rr = 0; rr < 4; rr++){                                    \
                int grow = row0 + quad*4 + rr;                                 \
                float v = acc1[j][rr] + invS*acc2[j][rr] + bcol[j];            \
                v = fmaxf(v, 0.f);                                             \
                out[(size_t)grow*H + col] = f2bf(v);                           \
                if (has_cs) cs[j] += v;                                        \
            }                                                                  \
        }                                                                      \
    }

    if (nt == 5){
        // wait for stage k: ops newer = 2*(4-k) stages + 8k stores
        asm volatile("s_waitcnt vmcnt(8)\ns_barrier" ::: "memory");  UP_BODY(0)
        asm volatile("s_waitcnt vmcnt(14)\ns_barrier" ::: "memory"); UP_BODY(1)
        asm volatile("s_waitcnt vmcnt(20)\ns_barrier" ::: "memory"); UP_BODY(2)
        asm volatile("s_waitcnt vmcnt(26)\ns_barrier" ::: "memory"); UP_BODY(3)
        asm volatile("s_waitcnt vmcnt(32)\ns_barrier" ::: "memory"); UP_BODY(4)
    } else {
        for (int k = 0; k < nt; k++){
            asm volatile("s_waitcnt vmcnt(0)\ns_barrier" ::: "memory");
            switch(k){
                case 0: UP_BODY(0) break;
                case 1: UP_BODY(1) break;
                case 2: UP_BODY(2) break;
                case 3: UP_BODY(3) break;
                default: UP_BODY(4) break;
            }
        }
    }
#undef UP_BODY

    if (has_cs){
        float* csum = (float*)As;   // buffer 0 is dead past tile 0's reads
        __syncthreads();
        if (tid < H) csum[tid] = 0.f;
        __syncthreads();
        #pragma unroll
        for (int j = 0; j < 2; j++){
            float v = cs[j];
            v += __shfl_xor(v, 16); v += __shfl_xor(v, 32);
            if (quad == 0) atomicAdd(&csum[strip + j*16 + l15], v);
        }
        __syncthreads();
        if (tid < H) atomicAdd(&colsum[tid], csum[tid]);
    }
}

// accumulate 8 fp8 (one int2) into 8 fp32 with weight
__device__ __forceinline__ void acc8f8(float* a, int2 u, float w){
    floatx2 p;
    p = __builtin_amdgcn_cvt_pk_f32_fp8(u.x, false); a[0] += w*p.x; a[1] += w*p.y;
    p = __builtin_amdgcn_cvt_pk_f32_fp8(u.x, true);  a[2] += w*p.x; a[3] += w*p.y;
    p = __builtin_amdgcn_cvt_pk_f32_fp8(u.y, false); a[4] += w*p.x; a[5] += w*p.y;
    p = __builtin_amdgcn_cvt_pk_f32_fp8(u.y, true);  a[6] += w*p.x; a[7] += w*p.y;
}

// ---------------- CSR gather: fp8 X rows -> UNNORMALIZED bf16 Mb -------------
__global__ __launch_bounds__(256) void k_gather(
    const int* __restrict__ rp, const int* __restrict__ csr, int Nrow,
    const float* __restrict__ y, const uchar_t* __restrict__ X,
    ushort_t* __restrict__ Mb, const unsigned* __restrict__ Mkey)
{
    int tid = threadIdx.x;
    int g = tid >> 4, gl = tid & 15;          // 16 groups x 16 lanes
    int r = blockIdx.x*16 + g;
    if (r >= Nrow) return;
    float Mv = funkey(Mkey[0]);
    int j0 = rp[r], j1 = rp[r+1];
    const int2* X8 = (const int2*)X;          // fp8 row = 16 int2 (128 fp8)
    float a[8] = {0.f,0.f,0.f,0.f,0.f,0.f,0.f,0.f};
    int j = j0;
    for (; j + 1 < j1; j += 2){
        int s0 = csr[j], s1 = csr[j+1];
        float e0 = expf(y[s0] - Mv);
        float e1 = expf(y[s1] - Mv);
        int2 u0 = X8[(size_t)s0*16 + gl];
        int2 u1 = X8[(size_t)s1*16 + gl];
        acc8f8(a, u0, e0);
        acc8f8(a, u1, e1);
    }
    if (j < j1){
        int s0 = csr[j];
        float e0 = expf(y[s0] - Mv);
        int2 u0 = X8[(size_t)s0*16 + gl];
        acc8f8(a, u0, e0);
    }
    int4 o;
    o.x = (int)((((unsigned)f2bf(a[1])) << 16) | (unsigned)f2bf(a[0]));
    o.y = (int)((((unsigned)f2bf(a[3])) << 16) | (unsigned)f2bf(a[2]));
    o.z = (int)((((unsigned)f2bf(a[5])) << 16) | (unsigned)f2bf(a[4]));
    o.w = (int)((((unsigned)f2bf(a[7])) << 16) | (unsigned)f2bf(a[6]));
    ((int4*)Mb)[(size_t)r*16 + gl] = o;
}

// ---------------- tiny MLP head ----------------
__global__ __launch_bounds__(256) void k_head(
    const float* __restrict__ meanP, const float* __restrict__ meanT,
    float invP, float invT,
    const float* __restrict__ Wpp, const float* __restrict__ bpp,
    const float* __restrict__ Wtp, const float* __restrict__ btp,
    const float* __restrict__ prefix,
    const float* __restrict__ W1, const float* __restrict__ b1,
    const float* __restrict__ W2, const float* __restrict__ b2,
    float* __restrict__ h2g)
{
    __shared__ float comb[384];
    __shared__ float h1s[256];
    int tid = threadIdx.x;
    if (tid < 128){
        float a = bpp[tid];
        for (int k = 0; k < 128; k++) a += meanP[k]*invP*Wpp[k*H + tid];
        comb[tid] = a;
        comb[256 + tid] = prefix[tid];
    } else {
        int c = tid - 128;
        float a = btp[c];
        for (int k = 0; k < 128; k++) a += meanT[k]*invT*Wtp[k*H + c];
        comb[128 + c] = a;
    }
    __syncthreads();
    {
        float a = b1[tid];
        for (int k = 0; k < 384; k++) a += comb[k]*W1[k*256 + tid];
        h1s[tid] = fmaxf(a, 0.f);
    }
    __syncthreads();
    if (tid < 128){
        float a = b2[tid];
        for (int k = 0; k < 256; k++) a += h1s[k]*W2[k*H + tid];
        h2g[tid] = fmaxf(a, 0.f);
    }
}

// ---------------- logits + sigmoid ----------------
__global__ __launch_bounds__(256) void k_logits(
    const float* __restrict__ h2g, const float* __restrict__ W3,
    const float* __restrict__ b3, float* __restrict__ out, int T)
{
    __shared__ float h2l[128];
    int tid = threadIdx.x;
    if (tid < 128) h2l[tid] = h2g[tid];
    __syncthreads();
    int t = blockIdx.x*256 + tid;
    if (t >= T) return;
    float a = b3[t];
    #pragma unroll 8
    for (int k = 0; k < 128; k++) a += h2l[k]*W3[(size_t)k*T + t];
    out[t] = 1.f/(1.f + expf(-a));
}

// ---------------- launch ----------------
extern "C" void kernel_launch(void* const* d_in, const int* in_sizes, int n_in,
                              void* d_out, int out_size, void* d_ws, size_t ws_size,
                              hipStream_t stream)
{
    (void)n_in; (void)out_size; (void)ws_size;
    const float* pf    = (const float*)d_in[0];
    const float* tf    = (const float*)d_in[1];
    const float* pe    = (const float*)d_in[2];
    const int*   pre   = (const int*)d_in[3];
    const int*   post  = (const int*)d_in[4];
    const float* W_pe  = (const float*)d_in[5];
    const float* b_pe  = (const float*)d_in[6];
    const float* W_te  = (const float*)d_in[7];
    const float* b_te  = (const float*)d_in[8];
    const float* W_pr  = (const float*)d_in[9];
    const float* b_pr  = (const float*)d_in[10];
    const float* p2t_W = (const float*)d_in[11];
    const float* p2t_b = (const float*)d_in[12];
    const float* t2p_W = (const float*)d_in[13];
    const float* t2p_b = (const float*)d_in[14];
    const float* pu_W  = (const float*)d_in[15];
    const float* pu_b  = (const float*)d_in[16];
    const float* tu_W  = (const float*)d_in[17];
    const float* tu_b  = (const float*)d_in[18];
    const float* pa_W  = (const float*)d_in[19];
    const float* pa_b  = (const float*)d_in[20];
    const float* ta_W  = (const float*)d_in[21];
    const float* ta_b  = (const float*)d_in[22];
    const float* W_pp  = (const float*)d_in[23];
    const float* b_pp  = (const float*)d_in[24];
    const float* W_tp  = (const float*)d_in[25];
    const float* b_tp  = (const float*)d_in[26];
    const float* W1    = (const float*)d_in[27];
    const float* b1    = (const float*)d_in[28];
    const float* W2    = (const float*)d_in[29];
    const float* b2    = (const float*)d_in[30];
    const float* W3    = (const float*)d_in[31];
    const float* b3    = (const float*)d_in[32];

    int P = in_sizes[0];
    int T = in_sizes[1] / 8;
    int E = in_sizes[3] / 2;
    int plen = in_sizes[2];
    int L = in_sizes[11] / (H*H);

    float* ws = (float*)d_ws;
    size_t fP = (size_t)P*H, fT = (size_t)T*H;
    size_t fN = (fP > fT) ? fP : fT;
    int   Nmax = (P > T) ? P : T;

    float* yb = ws;                       // [Nmax] fp32 scores
    float* y4 = yb + Nmax;                // [Nmax*4] per-wave score partials
    float* sc = y4 + (size_t)Nmax*4;      // 16 softmax slots + small vectors
    float* meanP   = sc + 16;
    float* meanT   = sc + 144;
    float* prefix  = sc + 272;
    float* h2g     = sc + 400;            // end at sc+544 (16B aligned)

    ushort_t* bh = (ushort_t*)(sc + 544);
    ushort_t* place_h = bh;               // [P,128] bf16
    ushort_t* trans_h = place_h + fP;     // [T,128]
    ushort_t* Mb      = trans_h + fT;     // [Nmax,128] bf16 messages (unnormalized)
    ushort_t* Pb2     = Mb + fN;          // [P,128] ping-pong place
    ushort_t* Tb2     = Pb2 + fP;         // [T,128] ping-pong trans
    ushort_t* WTb     = Tb2 + fT;         // L*98304 bf16 transposed weights
    uchar_t*  Xf8     = (uchar_t*)(WTb + (size_t)L*98304);  // [Nmax,128] fp8 X

    int* iw = (int*)(Xf8 + fN);
    int* cntPre  = iw;                 // [T]
    int* cntPost = cntPre + T;         // [P]
    int* rpPre   = cntPost + P;        // [T+1]
    int* rpPost  = rpPre + (T + 1);    // [P+1]
    int* csrPre  = rpPost + (P + 2);   // [E]
    int* csrPost = csrPre + E;         // [E]
    int* rankPre = csrPost + E;        // [E]
    int* rankPost= rankPre + E;        // [E]
    int* bsumA   = rankPost + E;       // [256]
    int* bsumB   = bsumA + 256;        // [256]

    const int* pre_src  = pre;          const int* pre_dst  = pre + E;
    const int* post_src = post;         const int* post_dst = post + E;

    int wtot = L*98304;
    int nbT = (T + 1023)/1024, nbP = (P + 1023)/1024;

    // GEMM grids: each block owns up to 5 tiles, all staged up-front.
    int tilesP = (P + 15) >> 4, tilesT = (T + 15) >> 4;
    int gridP = (tilesP + 4)/5, gridT = (tilesT + 4)/5;

    k_init_small<<<1, 128, 0, stream>>>(pe, plen, W_pr, b_pr, prefix, meanP, meanT, sc);
    k_wconv<<<(wtot + 255)/256, 256, 0, stream>>>(p2t_W, t2p_W, tu_W, pu_W, WTb, wtot);
    k_zero_ints<<<256, 256, 0, stream>>>(iw, P + T);
    k_hist2<<<2048, 256, 0, stream>>>(pre_dst, post_dst, E,
                                      cntPre, cntPost, rankPre, rankPost);
    k_scan_part<<<nbT, 256, 0, stream>>>(cntPre, T, bsumA);
    k_scan_bsum<<<1, 256, 0, stream>>>(bsumA, nbT);
    k_scan_final<<<nbT, 256, 0, stream>>>(cntPre, T, bsumA, rpPre, E);
    k_scan_part<<<nbP, 256, 0, stream>>>(cntPost, P, bsumB);
    k_scan_bsum<<<1, 256, 0, stream>>>(bsumB, nbP);
    k_scan_final<<<nbP, 256, 0, stream>>>(cntPost, P, bsumB, rpPost, E);
    k_fill2<<<1024, 256, 0, stream>>>(pre_src, pre_dst, post_src, post_dst, E,
                                      rpPre, rankPre, csrPre,
                                      rpPost, rankPost, csrPost);

    k_embed_place<<<(P*32 + 255)/256, 256, 0, stream>>>(pf, W_pe, b_pe, place_h, P);
    k_embed_trans<<<(T*32 + 255)/256, 256, 0, stream>>>(tf, W_te, b_te, trans_h, T);

    ushort_t* curP = place_h; ushort_t* altP = Pb2;
    ushort_t* curT = trans_h; ushort_t* altT = Tb2;

    for (int l = 0; l < L; l++){
        const ushort_t* WTl  = WTb + (size_t)l*98304;
        const ushort_t* p2tT = WTl;
        const ushort_t* t2pT = WTl + 16384;
        const ushort_t* tuT  = WTl + 32768;
        const ushort_t* puT  = WTl + 65536;
        const float* p2tb = p2t_b + (size_t)l*H;
        const float* t2pb = t2p_b + (size_t)l*H;
        const float* pub  = pu_b  + (size_t)l*H;
        const float* tub  = tu_b  + (size_t)l*H;
        const float* paW  = pa_W + (size_t)l*H;   const float* pab = pa_b + l;
        const float* taW  = ta_W + (size_t)l*H;   const float* tab = ta_b + l;
        unsigned* MkA = (unsigned*)(sc + l*4 + 0);   float* SpA = sc + l*4 + 1;
        unsigned* MkB = (unsigned*)(sc + l*4 + 2);   float* SpB = sc + l*4 + 3;
        int last = (l == L-1);

        // phase A: place -> transition (partial scores fused)
        k_gemm_msg<<<gridP, 256, 0, stream>>>(curP, p2tT, p2tb, Xf8, P, taW, y4);
        k_scoremax<<<128, 256, 0, stream>>>(y4, P, tab, yb, MkA);
        k_sumexp<<<256, 256, 0, stream>>>(pre_src, E, yb, MkA, SpA);
        k_gather<<<(T + 15)/16, 256, 0, stream>>>(rpPre, csrPre, T, yb, Xf8, Mb, MkA);

        // phase B: transform from OLD trans_h (+ its scores)
        k_gemm_msg<<<gridT, 256, 0, stream>>>(curT, t2pT, t2pb, Xf8, T, paW, y4);
        k_scoremax<<<128, 256, 0, stream>>>(y4, T, pab, yb, MkB);
        k_sumexp<<<256, 256, 0, stream>>>(post_src, E, yb, MkB, SpB);

        // transition update (consumes Mb = trans_msg, normalized by 1/SpA)
        k_gemm_up<<<gridT, 256, 0, stream>>>(curT, Mb, tuT, tub, SpA, altT, T,
                                             last ? meanT : nullptr);

        // place messages, then place update (normalized by 1/SpB)
        k_gather<<<(P + 15)/16, 256, 0, stream>>>(rpPost, csrPost, P, yb, Xf8, Mb, MkB);
        k_gemm_up<<<gridP, 256, 0, stream>>>(curP, Mb, puT, pub, SpB, altP, P,
                                             last ? meanP : nullptr);

        ushort_t* tmp;
        tmp = curT; curT = altT; altT = tmp;
        tmp = curP; curP = altP; altP = tmp;
    }

    k_head<<<1, 256, 0, stream>>>(meanP, meanT, 1.f/(float)P, 1.f/(float)T,
                                  W_pp, b_pp, W_tp, b_tp, prefix, W1, b1, W2, b2, h2g);
    k_logits<<<(T + 255)/256, 256, 0, stream>>>(h2g, W3, b3, (float*)d_out, T);
}

// Round 3
// 820.593 us; speedup vs baseline: 1.0464x; 1.0464x over previous
//
#include <hip/hip_runtime.h>
#include <cstddef>

#define H 128

typedef unsigned short ushort_t;
typedef unsigned char uchar_t;
typedef __attribute__((ext_vector_type(8))) short short8;
typedef __attribute__((ext_vector_type(4))) float floatx4;

// ---------------- helpers ----------------
__device__ __forceinline__ unsigned fkey(float f){
    unsigned u = __float_as_uint(f);
    return (u & 0x80000000u) ? ~u : (u | 0x80000000u);
}
__device__ __forceinline__ float funkey(unsigned k){
    unsigned u = (k & 0x80000000u) ? (k ^ 0x80000000u) : ~k;
    return __uint_as_float(u);
}
__device__ __forceinline__ ushort_t f2bf(float f){
    unsigned u = __float_as_uint(f);
    u += 0x7fffu + ((u >> 16) & 1u);      // round-to-nearest-even
    return (ushort_t)(u >> 16);
}
__device__ __forceinline__ float bf2f(ushort_t h){
    return __uint_as_float(((unsigned)h) << 16);
}
// async global -> LDS, 16B per lane. LDS dest = wave-uniform base + lane*16.
__device__ __forceinline__ void gll16(const void* g, void* l){
    __builtin_amdgcn_global_load_lds(
        (const __attribute__((address_space(1))) unsigned int*)g,
        (__attribute__((address_space(3))) unsigned int*)l, 16, 0, 0);
}
// accumulate 8 bf16 (one int4) into 8 fp32 with weight
__device__ __forceinline__ void acc8bf(float* a, int4 u, float w){
    a[0] += w*bf2f((ushort_t)(u.x & 0xffff)); a[1] += w*bf2f((ushort_t)(((unsigned)u.x) >> 16));
    a[2] += w*bf2f((ushort_t)(u.y & 0xffff)); a[3] += w*bf2f((ushort_t)(((unsigned)u.y) >> 16));
    a[4] += w*bf2f((ushort_t)(u.z & 0xffff)); a[5] += w*bf2f((ushort_t)(((unsigned)u.z) >> 16));
    a[6] += w*bf2f((ushort_t)(u.w & 0xffff)); a[7] += w*bf2f((ushort_t)(((unsigned)u.w) >> 16));
}

// ---------------- embeddings (write bf16 states) ----------------
__global__ __launch_bounds__(256) void k_embed_place(
    const float* __restrict__ pf, const float* __restrict__ Wpe,
    const float* __restrict__ bpe, ushort_t* __restrict__ out, int P)
{
    int idx = blockIdx.x*256 + threadIdx.x;     // 4-elem group index over P*32
    if (idx >= P*32) return;
    int p = idx >> 5, q = (idx & 31) << 2;
    float v = pf[p];
    float4 w = *(const float4*)(Wpe + q);
    float4 b = *(const float4*)(bpe + q);
    ushort4 o;
    o.x = f2bf(v*w.x + b.x); o.y = f2bf(v*w.y + b.y);
    o.z = f2bf(v*w.z + b.z); o.w = f2bf(v*w.w + b.w);
    *(ushort4*)(out + (size_t)p*H + q) = o;
}

__global__ __launch_bounds__(256) void k_embed_trans(
    const float* __restrict__ tf, const float* __restrict__ Wte,
    const float* __restrict__ bte, ushort_t* __restrict__ out, int T)
{
    __shared__ float Wl[8*H];
    __shared__ float Bl[H];
    int tid = threadIdx.x;
    #pragma unroll
    for (int t = 0; t < 4; t++) Wl[tid + t*256] = Wte[tid + t*256];
    if (tid < H) Bl[tid] = bte[tid];
    __syncthreads();
    int idx = blockIdx.x*256 + tid;
    if (idx >= T*32) return;
    int t = idx >> 5, q = (idx & 31) << 2;
    float4 acc = *(float4*)(&Bl[q]);
    #pragma unroll
    for (int k = 0; k < 8; k++){
        float s = tf[(size_t)t*8 + k];
        float4 w = *(float4*)(&Wl[k*H + q]);
        acc.x += s*w.x; acc.y += s*w.y; acc.z += s*w.z; acc.w += s*w.w;
    }
    ushort4 o;
    o.x = f2bf(acc.x); o.y = f2bf(acc.y); o.z = f2bf(acc.z); o.w = f2bf(acc.w);
    *(ushort4*)(out + (size_t)t*H + q) = o;
}

// prefix embedding + zero small accumulators + all softmax slots
__global__ void k_init_small(const float* __restrict__ pe, int plen,
                             const float* __restrict__ Wpr, const float* __restrict__ bpr,
                             float* __restrict__ prefix, float* __restrict__ meanP,
                             float* __restrict__ meanT, float* __restrict__ slots)
{
    int c = threadIdx.x;  // 128 threads
    float a = bpr[c];
    for (int k = 0; k < plen; k++) a += pe[k]*Wpr[k*H + c];
    prefix[c] = a;
    meanP[c] = 0.f;
    meanT[c] = 0.f;
    if (c < 16) slots[c] = 0.f;   // fkey-space 0 == -inf; Sp slots start at 0
}

// ---------------- weight convert: A1-half of combined update weights --------
// WT per layer: [side0: tu-combined 128x256][side1: pu-combined 128x256]
// k entries 0..127 (A1/top half) written here; 128..255 (Wc) by k_wprep.
__global__ __launch_bounds__(256) void k_wconv(
    const float* __restrict__ tu_W, const float* __restrict__ pu_W,
    ushort_t* __restrict__ WT, int total)
{
    int e = blockIdx.x*256 + threadIdx.x;
    if (e >= total) return;
    int l = e / 32768, oo = e - l*32768;
    int side = oo >> 14, o2 = oo & 16383;
    int n = o2 >> 7, k = o2 & 127;
    const float* Bm = side ? (pu_W + (size_t)l*32768) : (tu_W + (size_t)l*32768);
    WT[(size_t)l*65536 + (size_t)side*32768 + n*256 + k] = f2bf(Bm[(size_t)k*H + n]);
}

// ---------------- folded-weight prep (linearity refactor) --------------------
// side 0 (pre/p2t path): Wc = p2t_W @ tu_W[128:], wv = p2t_W @ ta_W,
//   bc = p2t_b @ tu_W[128:], c0 = p2t_b.ta_W + ta_b
// side 1 (post/t2p path): same with t2p/pu/pa.
// Wc written into WT slots k=128..255 (bf16, [n][k] layout).
__global__ __launch_bounds__(256) void k_wprep(
    const float* __restrict__ p2t_W, const float* __restrict__ t2p_W,
    const float* __restrict__ tu_W,  const float* __restrict__ pu_W,
    const float* __restrict__ p2t_b, const float* __restrict__ t2p_b,
    const float* __restrict__ ta_W,  const float* __restrict__ ta_b,
    const float* __restrict__ pa_W,  const float* __restrict__ pa_b,
    ushort_t* __restrict__ WT, float* __restrict__ wv,
    float* __restrict__ c0v, float* __restrict__ bcv)
{
    int b = blockIdx.x;
    int l = b >> 3, sub = b & 7;
    int side = sub >> 2, q = sub & 3;
    const float* A  = side ? (t2p_W + (size_t)l*16384) : (p2t_W + (size_t)l*16384);
    const float* Bm = side ? (pu_W  + (size_t)l*32768) : (tu_W  + (size_t)l*32768);
    const float* ab = side ? (t2p_b + (size_t)l*H) : (p2t_b + (size_t)l*H);
    const float* av = side ? (pa_W  + (size_t)l*H) : (ta_W  + (size_t)l*H);
    float asc       = side ? pa_b[l] : ta_b[l];
    int tid = threadIdx.x;
    ushort_t* Wdst = WT + (size_t)l*65536 + (size_t)side*32768;
    for (int idx = q*4096 + tid; idx < (q+1)*4096; idx += 256){
        int n = idx >> 7, k = idx & 127;
        float s = 0.f;
        for (int j = 0; j < 128; j++) s += A[(size_t)k*H + j] * Bm[(size_t)(128+j)*H + n];
        Wdst[(size_t)n*256 + 128 + k] = f2bf(s);
    }
    if (q == 0){
        int o = (l*2 + side)*H;
        if (tid < H){
            float s = 0.f;
            for (int n = 0; n < 128; n++) s += A[(size_t)tid*H + n] * av[n];
            wv[o + tid] = s;
            float s2 = 0.f;
            for (int j = 0; j < 128; j++) s2 += ab[j] * Bm[(size_t)(128+j)*H + tid];
            bcv[o + tid] = s2;
        }
        if (tid == 0){
            float s = 0.f;
            for (int n = 0; n < 128; n++) s += ab[n]*av[n];
            c0v[l*2 + side] = s + asc;
        }
    }
}

// ---------------- CSR build ----------------
__global__ __launch_bounds__(256) void k_zero_ints(int* __restrict__ p, int n)
{
    int i = blockIdx.x*256 + threadIdx.x;
    int stride = gridDim.x*256;
    for (; i < n; i += stride) p[i] = 0;
}

__global__ __launch_bounds__(256) void k_hist2(
    const int* __restrict__ preD, const int* __restrict__ postD, int E,
    int* __restrict__ cntPre, int* __restrict__ cntPost,
    int* __restrict__ rankPre, int* __restrict__ rankPost)
{
    int i = blockIdx.x*256 + threadIdx.x;
    int stride = gridDim.x*256;
    for (; i < E; i += stride){
        rankPre[i] = atomicAdd(&cntPre[preD[i]], 1);
        rankPost[i] = atomicAdd(&cntPost[postD[i]], 1);
    }
}

__global__ __launch_bounds__(256) void k_scan_part(
    const int* __restrict__ cnt, int N, int* __restrict__ bsum)
{
    __shared__ int wsum[4];
    int tid = threadIdx.x, lane = tid & 63, wid = tid >> 6;
    int base = blockIdx.x*1024 + tid*4;
    int4 v = make_int4(0,0,0,0);
    if (base + 3 < N) v = *(const int4*)(cnt + base);
    else {
        if (base+0 < N) v.x = cnt[base+0];
        if (base+1 < N) v.y = cnt[base+1];
        if (base+2 < N) v.z = cnt[base+2];
    }
    int s = v.x + v.y + v.z + v.w;
    #pragma unroll
    for (int o = 1; o < 64; o <<= 1) s += __shfl_xor(s, o);
    if (lane == 0) wsum[wid] = s;
    __syncthreads();
    if (tid == 0) bsum[blockIdx.x] = wsum[0] + wsum[1] + wsum[2] + wsum[3];
}

__global__ __launch_bounds__(256) void k_scan_bsum(int* __restrict__ bsum, int nb)
{
    __shared__ int wsum[4];
    int tid = threadIdx.x, lane = tid & 63, wid = tid >> 6;
    int x = (tid < nb) ? bsum[tid] : 0;
    int inc = x;
    #pragma unroll
    for (int o = 1; o < 64; o <<= 1){
        int u = __shfl_up(inc, o);
        if (lane >= o) inc += u;
    }
    if (lane == 63) wsum[wid] = inc;
    __syncthreads();
    int woff = 0;
    if (wid > 0) woff += wsum[0];
    if (wid > 1) woff += wsum[1];
    if (wid > 2) woff += wsum[2];
    if (tid < nb) bsum[tid] = woff + inc - x;
}

__global__ __launch_bounds__(256) void k_scan_final(
    const int* __restrict__ cnt, int N, const int* __restrict__ bsum,
    int* __restrict__ rp, int E)
{
    __shared__ int wsum[4];
    int tid = threadIdx.x, lane = tid & 63, wid = tid >> 6;
    int base = blockIdx.x*1024 + tid*4;
    int4 v = make_int4(0,0,0,0);
    if (base + 3 < N) v = *(const int4*)(cnt + base);
    else {
        if (base+0 < N) v.x = cnt[base+0];
        if (base+1 < N) v.y = cnt[base+1];
        if (base+2 < N) v.z = cnt[base+2];
    }
    int t0 = v.x, t1 = t0 + v.y, t2 = t1 + v.z, t3 = t2 + v.w;
    int inc = t3;
    #pragma unroll
    for (int o = 1; o < 64; o <<= 1){
        int u = __shfl_up(inc, o);
        if (lane >= o) inc += u;
    }
    if (lane == 63) wsum[wid] = inc;
    __syncthreads();
    int woff = 0;
    if (wid > 0) woff += wsum[0];
    if (wid > 1) woff += wsum[1];
    if (wid > 2) woff += wsum[2];
    int off = bsum[blockIdx.x] + woff + inc - t3;
    if (base+0 < N) rp[base+0] = off;
    if (base+1 < N) rp[base+1] = off + t0;
    if (base+2 < N) rp[base+2] = off + t1;
    if (base+3 < N) rp[base+3] = off + t2;
    if (blockIdx.x == 0 && tid == 0) rp[N] = E;
}

__global__ __launch_bounds__(256) void k_fill2(
    const int* __restrict__ preS, const int* __restrict__ preD,
    const int* __restrict__ postS, const int* __restrict__ postD, int E,
    const int* __restrict__ rpPre, const int* __restrict__ rankPre, int* __restrict__ csrPre,
    const int* __restrict__ rpPost, const int* __restrict__ rankPost, int* __restrict__ csrPost)
{
    int i = blockIdx.x*256 + threadIdx.x;
    int stride = gridDim.x*256;
    for (; i < E; i += stride){
        csrPre[rpPre[preD[i]] + rankPre[i]] = preS[i];
        csrPost[rpPost[postD[i]] + rankPost[i]] = postS[i];
    }
}

// ---------------- score GEMV: y[r] = h[r].wv + c0, fused global max ----------
__global__ __launch_bounds__(256) void k_gemv(
    const ushort_t* __restrict__ A, int M,
    const float* __restrict__ wv, const float* __restrict__ c0v, int c0i,
    float* __restrict__ y, unsigned* __restrict__ Mkey)
{
    __shared__ float wm[4];
    int tid = threadIdx.x, lane = tid & 63, wid = tid >> 6;
    int g = tid >> 4, gl = tid & 15;
    float w8[8];
    #pragma unroll
    for (int i = 0; i < 8; i++) w8[i] = wv[gl*8 + i];
    float c0 = c0v[c0i];
    int stride = gridDim.x*16;
    float lmax = -3.402823466e38f;
    for (int r = blockIdx.x*16 + g; r < M; r += stride){
        short8 u = *(const short8*)(A + (size_t)r*H + gl*8);
        float s = 0.f;
        #pragma unroll
        for (int i = 0; i < 8; i++) s += bf2f((ushort_t)u[i]) * w8[i];
        s += __shfl_xor(s, 1); s += __shfl_xor(s, 2);
        s += __shfl_xor(s, 4); s += __shfl_xor(s, 8);
        s += c0;
        if (gl == 0) y[r] = s;
        lmax = fmaxf(lmax, s);
    }
    #pragma unroll
    for (int o = 1; o < 64; o <<= 1) lmax = fmaxf(lmax, __shfl_xor(lmax, o));
    if (lane == 0) wm[wid] = lmax;
    __syncthreads();
    if (tid == 0){
        float m = fmaxf(fmaxf(wm[0], wm[1]), fmaxf(wm[2], wm[3]));
        atomicMax(Mkey, fkey(m));
    }
}

// ---------------- softmax denominator over edge src list --------------------
__global__ __launch_bounds__(256) void k_sumexp(
    const int* __restrict__ src, int E, const float* __restrict__ y,
    const unsigned* __restrict__ Mkey, float* __restrict__ Sp)
{
    __shared__ float red[4];
    int tid = threadIdx.x, lane = tid & 63, wid = tid >> 6;
    int gid = blockIdx.x*256 + tid, stride = gridDim.x*256;
    float Mv = funkey(Mkey[0]);
    float ls = 0.f;
    for (int e = gid; e < E; e += stride) ls += expf(y[src[e]] - Mv);
    #pragma unroll
    for (int o = 1; o < 64; o <<= 1) ls += __shfl_xor(ls, o);
    if (lane == 0) red[wid] = ls;
    __syncthreads();
    if (tid == 0) atomicAdd(Sp, red[0] + red[1] + red[2] + red[3]);
}

// ---------------- CSR gather of bf16 state rows + sdeg -----------------------
// G[r] = sum_e exp(y[src]-M) * Hsrc[src]  (UNNORMALIZED),  sdeg[r] = sum exp.
__global__ __launch_bounds__(256) void k_gatherH(
    const int* __restrict__ rp, const int* __restrict__ csr, int Nrow,
    const float* __restrict__ y, const ushort_t* __restrict__ Hsrc,
    ushort_t* __restrict__ G, float* __restrict__ sdeg,
    const unsigned* __restrict__ Mkey)
{
    int tid = threadIdx.x;
    int g = tid >> 4, gl = tid & 15;          // 16 groups x 16 lanes
    int r = blockIdx.x*16 + g;
    if (r >= Nrow) return;
    float Mv = funkey(Mkey[0]);
    int j0 = rp[r], j1 = rp[r+1];
    const int4* H4 = (const int4*)Hsrc;       // bf16 row = 16 int4 (128 bf16)
    float a[8] = {0.f,0.f,0.f,0.f,0.f,0.f,0.f,0.f};
    float se = 0.f;
    int j = j0;
    for (; j + 1 < j1; j += 2){
        int s0 = csr[j], s1 = csr[j+1];
        float e0 = expf(y[s0] - Mv);
        float e1 = expf(y[s1] - Mv);
        int4 u0 = H4[(size_t)s0*16 + gl];
        int4 u1 = H4[(size_t)s1*16 + gl];
        se += e0 + e1;
        acc8bf(a, u0, e0);
        acc8bf(a, u1, e1);
    }
    if (j < j1){
        int s0 = csr[j];
        float e0 = expf(y[s0] - Mv);
        int4 u0 = H4[(size_t)s0*16 + gl];
        se += e0;
        acc8bf(a, u0, e0);
    }
    int4 o;
    o.x = (int)((((unsigned)f2bf(a[1])) << 16) | (unsigned)f2bf(a[0]));
    o.y = (int)((((unsigned)f2bf(a[3])) << 16) | (unsigned)f2bf(a[2]));
    o.z = (int)((((unsigned)f2bf(a[5])) << 16) | (unsigned)f2bf(a[4]));
    o.w = (int)((((unsigned)f2bf(a[7])) << 16) | (unsigned)f2bf(a[6]));
    ((int4*)G)[(size_t)r*16 + gl] = o;
    if (gl == 0) sdeg[r] = se;
}

// ---------------- update GEMM ------------------------------------------------
// out = relu(A1 + A1@Wtop + invS*(G@Wc + sdeg*bc) + b)
// R1-proven 3-buffer LDS ring (2-deep prefetch, counted vmcnt, raw s_barrier),
// XOR-swizzled via pre-swizzled global source. Residual A1 via identity-MFMA.
// REQUIRES M % 16 == 0.
__global__ __launch_bounds__(256, 4) void k_gemm_up(
    const ushort_t* __restrict__ A1, const ushort_t* __restrict__ A2,
    const ushort_t* __restrict__ WT, const float* __restrict__ bias,
    const float* __restrict__ bcp, const float* __restrict__ Sp,
    const float* __restrict__ sdeg,
    ushort_t* __restrict__ out, int M, float* __restrict__ colsum)
{
    __shared__ __align__(16) char As[3*8192];   // 3 x (A1 4KB | A2 4KB)
    __shared__ float csum[H];
    int tid = threadIdx.x;
    int lane = tid & 63, wid = tid >> 6;
    int quad = lane >> 4, l15 = lane & 15;
    int strip = wid*32;
    short8 bfr1[2][4], bfr2[2][4];
    float bcol[2], bc2[2];
    #pragma unroll
    for (int j = 0; j < 2; j++){
        int col = strip + j*16 + l15;
        #pragma unroll
        for (int kk = 0; kk < 4; kk++){
            bfr1[j][kk] = *(const short8*)(WT + (size_t)col*256 + kk*32 + quad*8);
            bfr2[j][kk] = *(const short8*)(WT + (size_t)col*256 + 128 + kk*32 + quad*8);
        }
        bcol[j] = bias[col];
        bc2[j]  = bcp[col];
    }
    // identity B-fragments: transpose the wave's A1 fragment window into C-layout
    short8 If0, If1;
    #pragma unroll
    for (int e = 0; e < 8; e++){
        int kloc = quad*8 + e;
        If0[e] = (kloc == l15)      ? (short)0x3F80 : (short)0;
        If1[e] = (kloc == l15 + 16) ? (short)0x3F80 : (short)0;
    }
    float invS = 1.f / Sp[0];
    const bool has_cs = (colsum != nullptr);
    if (has_cs && tid < H) csum[tid] = 0.f;
    float cs[2] = {0.f, 0.f};

    int tiles = (M + 15) >> 4;
    int G = gridDim.x;
    int t0 = blockIdx.x;
    if (t0 >= tiles) return;
    int srow = tid >> 4;
    int su = (tid & 15) ^ srow;
    const ushort_t* g1b = A1 + (size_t)srow*H + su*8;
    const ushort_t* g2b = A2 + (size_t)srow*H + su*8;
    char* AsB = As;

    #define STAGE_UP(bo, t) do { \
        gll16(g1b + (size_t)(t)*(16*H), AsB + (bo) + (wid<<10)); \
        gll16(g2b + (size_t)(t)*(16*H), AsB + (bo) + 4096 + (wid<<10)); \
    } while(0)

    STAGE_UP(0, t0);
    int t1p = t0 + G;
    if (t1p < tiles){
        STAGE_UP(8192, t1p);
        asm volatile("s_waitcnt vmcnt(2)\ns_barrier" ::: "memory");
    } else {
        asm volatile("s_waitcnt vmcnt(0)\ns_barrier" ::: "memory");
    }

    int t = t0, bo = 0;
    for (;;){
        const char* rb = AsB + bo;
        int row0 = t << 4;
        float4 sd4 = *(const float4*)(sdeg + row0 + quad*4);
        float sdv[4] = {sd4.x, sd4.y, sd4.z, sd4.w};
        short8 a1f[4], a2f[4];
        #pragma unroll
        for (int kk = 0; kk < 4; kk++){
            int sw = ((((kk<<2)+quad) ^ l15) << 4);
            a1f[kk] = *(const short8*)(rb + (l15<<8) + sw);
            a2f[kk] = *(const short8*)(rb + 4096 + (l15<<8) + sw);
        }
        short8 ares = *(const short8*)(rb + (l15<<8) + ((((wid<<2)+quad) ^ l15) << 4));
        floatx4 acc1[2], acc2[2];
        acc1[0] = __builtin_amdgcn_mfma_f32_16x16x32_bf16(ares, If0, (floatx4)0.f, 0,0,0);
        acc1[1] = __builtin_amdgcn_mfma_f32_16x16x32_bf16(ares, If1, (floatx4)0.f, 0,0,0);
        acc2[0] = (floatx4)0.f; acc2[1] = (floatx4)0.f;
        #pragma unroll
        for (int j = 0; j < 2; j++){
            #pragma unroll
            for (int kk = 0; kk < 4; kk++)
                acc1[j] = __builtin_amdgcn_mfma_f32_16x16x32_bf16(a1f[kk], bfr1[j][kk], acc1[j], 0,0,0);
            #pragma unroll
            for (int kk = 0; kk < 4; kk++)
                acc2[j] = __builtin_amdgcn_mfma_f32_16x16x32_bf16(a2f[kk], bfr2[j][kk], acc2[j], 0,0,0);
        }
        #pragma unroll
        for (int j = 0; j < 2; j++){
            int col = strip + j*16 + l15;
            #pragma unroll
            for (int rr = 0; rr < 4; rr++){
                int grow = row0 + quad*4 + rr;
                float v = acc1[j][rr] + invS*(acc2[j][rr] + sdv[rr]*bc2[j]) + bcol[j];
                v = fmaxf(v, 0.f);
                out[(size_t)grow*H + col] = f2bf(v);    // 8 ushort stores/lane/tile
                if (has_cs) cs[j] += v;
            }
        }
        int tn = t + G;
        if (tn >= tiles) break;
        int tnn = tn + G;
        int bo2 = bo + 8192; if (bo2 >= 24576) bo2 = 0;
        int bo3 = bo2 + 8192; if (bo3 >= 24576) bo3 = 0;
        // wait for stage(tn): ops newer = 1 sdeg + 8 stores (+2 stage if issued)
        if (tnn < tiles){
            STAGE_UP(bo3, tnn);
            asm volatile("s_waitcnt vmcnt(11)\ns_barrier" ::: "memory");
        } else {
            asm volatile("s_waitcnt vmcnt(9)\ns_barrier" ::: "memory");
        }
        t = tn; bo = bo2;
    }
    #undef STAGE_UP
    if (has_cs){
        #pragma unroll
        for (int j = 0; j < 2; j++){
            float v = cs[j];
            v += __shfl_xor(v, 16); v += __shfl_xor(v, 32);
            if (quad == 0) atomicAdd(&csum[strip + j*16 + l15], v);
        }
        __syncthreads();
        if (tid < H) atomicAdd(&colsum[tid], csum[tid]);
    }
}

// ---------------- tiny MLP head ----------------
__global__ __launch_bounds__(256) void k_head(
    const float* __restrict__ meanP, const float* __restrict__ meanT,
    float invP, float invT,
    const float* __restrict__ Wpp, const float* __restrict__ bpp,
    const float* __restrict__ Wtp, const float* __restrict__ btp,
    const float* __restrict__ prefix,
    const float* __restrict__ W1, const float* __restrict__ b1,
    const float* __restrict__ W2, const float* __restrict__ b2,
    float* __restrict__ h2g)
{
    __shared__ float comb[384];
    __shared__ float h1s[256];
    int tid = threadIdx.x;
    if (tid < 128){
        float a = bpp[tid];
        for (int k = 0; k < 128; k++) a += meanP[k]*invP*Wpp[k*H + tid];
        comb[tid] = a;
        comb[256 + tid] = prefix[tid];
    } else {
        int c = tid - 128;
        float a = btp[c];
        for (int k = 0; k < 128; k++) a += meanT[k]*invT*Wtp[k*H + c];
        comb[128 + c] = a;
    }
    __syncthreads();
    {
        float a = b1[tid];
        for (int k = 0; k < 384; k++) a += comb[k]*W1[k*256 + tid];
        h1s[tid] = fmaxf(a, 0.f);
    }
    __syncthreads();
    if (tid < 128){
        float a = b2[tid];
        for (int k = 0; k < 256; k++) a += h1s[k]*W2[k*H + tid];
        h2g[tid] = fmaxf(a, 0.f);
    }
}

// ---------------- logits + sigmoid ----------------
__global__ __launch_bounds__(256) void k_logits(
    const float* __restrict__ h2g, const float* __restrict__ W3,
    const float* __restrict__ b3, float* __restrict__ out, int T)
{
    __shared__ float h2l[128];
    int tid = threadIdx.x;
    if (tid < 128) h2l[tid] = h2g[tid];
    __syncthreads();
    int t = blockIdx.x*256 + tid;
    if (t >= T) return;
    float a = b3[t];
    #pragma unroll 8
    for (int k = 0; k < 128; k++) a += h2l[k]*W3[(size_t)k*T + t];
    out[t] = 1.f/(1.f + expf(-a));
}

// ---------------- launch ----------------
extern "C" void kernel_launch(void* const* d_in, const int* in_sizes, int n_in,
                              void* d_out, int out_size, void* d_ws, size_t ws_size,
                              hipStream_t stream)
{
    (void)n_in; (void)out_size; (void)ws_size;
    const float* pf    = (const float*)d_in[0];
    const float* tf    = (const float*)d_in[1];
    const float* pe    = (const float*)d_in[2];
    const int*   pre   = (const int*)d_in[3];
    const int*   post  = (const int*)d_in[4];
    const float* W_pe  = (const float*)d_in[5];
    const float* b_pe  = (const float*)d_in[6];
    const float* W_te  = (const float*)d_in[7];
    const float* b_te  = (const float*)d_in[8];
    const float* W_pr  = (const float*)d_in[9];
    const float* b_pr  = (const float*)d_in[10];
    const float* p2t_W = (const float*)d_in[11];
    const float* p2t_b = (const float*)d_in[12];
    const float* t2p_W = (const float*)d_in[13];
    const float* t2p_b = (const float*)d_in[14];
    const float* pu_W  = (const float*)d_in[15];
    const float* pu_b  = (const float*)d_in[16];
    const float* tu_W  = (const float*)d_in[17];
    const float* tu_b  = (const float*)d_in[18];
    const float* pa_W  = (const float*)d_in[19];
    const float* pa_b  = (const float*)d_in[20];
    const float* ta_W  = (const float*)d_in[21];
    const float* ta_b  = (const float*)d_in[22];
    const float* W_pp  = (const float*)d_in[23];
    const float* b_pp  = (const float*)d_in[24];
    const float* W_tp  = (const float*)d_in[25];
    const float* b_tp  = (const float*)d_in[26];
    const float* W1    = (const float*)d_in[27];
    const float* b1    = (const float*)d_in[28];
    const float* W2    = (const float*)d_in[29];
    const float* b2    = (const float*)d_in[30];
    const float* W3    = (const float*)d_in[31];
    const float* b3    = (const float*)d_in[32];

    int P = in_sizes[0];
    int T = in_sizes[1] / 8;
    int E = in_sizes[3] / 2;
    int plen = in_sizes[2];
    int L = in_sizes[11] / (H*H);

    float* ws = (float*)d_ws;
    size_t fP = (size_t)P*H, fT = (size_t)T*H;
    size_t fN = (fP > fT) ? fP : fT;
    int   Nmax = (P > T) ? P : T;

    float* yb   = ws;                     // [Nmax] fp32 scores
    float* sdeg = yb + Nmax;              // [Nmax] per-dst sum of exp
    float* sc   = sdeg + Nmax;            // 16 softmax slots
    float* meanP   = sc + 16;
    float* meanT   = sc + 144;
    float* prefix  = sc + 272;
    float* h2g     = sc + 400;            // end at sc+544
    float* wvv  = sc + 544;               // [L*2*128] folded score vectors
    float* c0v  = wvv + (size_t)L*256;    // [32] folded score consts (padded)
    float* bcv  = c0v + 32;               // [L*2*128] folded bias rows

    ushort_t* bh = (ushort_t*)(bcv + (size_t)L*256);
    ushort_t* place_h = bh;               // [P,128] bf16
    ushort_t* trans_h = place_h + fP;     // [T,128]
    ushort_t* Gb      = trans_h + fT;     // [Nmax,128] bf16 gathered states
    ushort_t* Pb2     = Gb + fN;          // [P,128] ping-pong place
    ushort_t* Tb2     = Pb2 + fP;         // [T,128] ping-pong trans
    ushort_t* WTb     = Tb2 + fT;         // L*65536 bf16 combined update weights

    int* iw = (int*)(WTb + (size_t)L*65536);
    int* cntPre  = iw;                 // [T]
    int* cntPost = cntPre + T;         // [P]
    int* rpPre   = cntPost + P;        // [T+1]
    int* rpPost  = rpPre + (T + 1);    // [P+1]
    int* csrPre  = rpPost + (P + 2);   // [E]
    int* csrPost = csrPre + E;         // [E]
    int* rankPre = csrPost + E;        // [E]
    int* rankPost= rankPre + E;        // [E]
    int* bsumA   = rankPost + E;       // [256]
    int* bsumB   = bsumA + 256;        // [256]

    const int* pre_src  = pre;          const int* pre_dst  = pre + E;
    const int* post_src = post;         const int* post_dst = post + E;

    int wtot = L*32768;
    int nbT = (T + 1023)/1024, nbP = (P + 1023)/1024;

    // update-GEMM grids: R1-proven ring, 5 tiles/block
    int tilesP = (P + 15) >> 4, tilesT = (T + 15) >> 4;
    int gridP = (tilesP + 4)/5, gridT = (tilesT + 4)/5;

    k_init_small<<<1, 128, 0, stream>>>(pe, plen, W_pr, b_pr, prefix, meanP, meanT, sc);
    k_wconv<<<(wtot + 255)/256, 256, 0, stream>>>(tu_W, pu_W, WTb, wtot);
    k_wprep<<<L*8, 256, 0, stream>>>(p2t_W, t2p_W, tu_W, pu_W, p2t_b, t2p_b,
                                     ta_W, ta_b, pa_W, pa_b, WTb, wvv, c0v, bcv);
    k_zero_ints<<<256, 256, 0, stream>>>(iw, P + T);
    k_hist2<<<2048, 256, 0, stream>>>(pre_dst, post_dst, E,
                                      cntPre, cntPost, rankPre, rankPost);
    k_scan_part<<<nbT, 256, 0, stream>>>(cntPre, T, bsumA);
    k_scan_bsum<<<1, 256, 0, stream>>>(bsumA, nbT);
    k_scan_final<<<nbT, 256, 0, stream>>>(cntPre, T, bsumA, rpPre, E);
    k_scan_part<<<nbP, 256, 0, stream>>>(cntPost, P, bsumB);
    k_scan_bsum<<<1, 256, 0, stream>>>(bsumB, nbP);
    k_scan_final<<<nbP, 256, 0, stream>>>(cntPost, P, bsumB, rpPost, E);
    k_fill2<<<1024, 256, 0, stream>>>(pre_src, pre_dst, post_src, post_dst, E,
                                      rpPre, rankPre, csrPre,
                                      rpPost, rankPost, csrPost);

    k_embed_place<<<(P*32 + 255)/256, 256, 0, stream>>>(pf, W_pe, b_pe, place_h, P);
    k_embed_trans<<<(T*32 + 255)/256, 256, 0, stream>>>(tf, W_te, b_te, trans_h, T);

    ushort_t* curP = place_h; ushort_t* altP = Pb2;
    ushort_t* curT = trans_h; ushort_t* altT = Tb2;

    for (int l = 0; l < L; l++){
        const ushort_t* tuT = WTb + (size_t)l*65536;           // side 0
        const ushort_t* puT = tuT + 32768;                     // side 1
        const float* pub  = pu_b  + (size_t)l*H;
        const float* tub  = tu_b  + (size_t)l*H;
        const float* wvA  = wvv + (size_t)(l*2 + 0)*H;
        const float* wvB  = wvv + (size_t)(l*2 + 1)*H;
        const float* bcA  = bcv + (size_t)(l*2 + 0)*H;
        const float* bcB  = bcv + (size_t)(l*2 + 1)*H;
        unsigned* MkA = (unsigned*)(sc + l*4 + 0);   float* SpA = sc + l*4 + 1;
        unsigned* MkB = (unsigned*)(sc + l*4 + 2);   float* SpB = sc + l*4 + 3;
        int last = (l == L-1);

        // phase A: place scores -> softmax stats -> gather places into G (per trans)
        k_gemv<<<512, 256, 0, stream>>>(curP, P, wvA, c0v, l*2 + 0, yb, MkA);
        k_sumexp<<<256, 256, 0, stream>>>(pre_src, E, yb, MkA, SpA);
        k_gatherH<<<(T + 15)/16, 256, 0, stream>>>(rpPre, csrPre, T, yb, curP,
                                                   Gb, sdeg, MkA);

        // phase B: trans scores (from OLD trans_h)
        k_gemv<<<512, 256, 0, stream>>>(curT, T, wvB, c0v, l*2 + 1, yb, MkB);
        k_sumexp<<<256, 256, 0, stream>>>(post_src, E, yb, MkB, SpB);

        // transition update (consumes G/sdeg from phase A, normalized by 1/SpA)
        k_gemm_up<<<gridT, 256, 0, stream>>>(curT, Gb, tuT, tub, bcA, SpA, sdeg,
                                             altT, T, last ? meanT : nullptr);

        // gather transes into G (per place), then place update
        k_gatherH<<<(P + 15)/16, 256, 0, stream>>>(rpPost, csrPost, P, yb, curT,
                                                   Gb, sdeg, MkB);
        k_gemm_up<<<gridP, 256, 0, stream>>>(curP, Gb, puT, pub, bcB, SpB, sdeg,
                                             altP, P, last ? meanP : nullptr);

        ushort_t* tmp;
        tmp = curT; curT = altT; altT = tmp;
        tmp = curP; curP = altP; altP = tmp;
    }

    k_head<<<1, 256, 0, stream>>>(meanP, meanT, 1.f/(float)P, 1.f/(float)T,
                                  W_pp, b_pp, W_tp, b_tp, prefix, W1, b1, W2, b2, h2g);
    k_logits<<<(T + 255)/256, 256, 0, stream>>>(h2g, W3, b3, (float*)d_out, T);
}

// Round 4
// 771.132 us; speedup vs baseline: 1.1135x; 1.0641x over previous
//
#include <hip/hip_runtime.h>
#include <cstddef>

#define H 128

typedef unsigned short ushort_t;
typedef unsigned char uchar_t;
typedef __attribute__((ext_vector_type(8))) short short8;
typedef __attribute__((ext_vector_type(4))) float floatx4;
typedef __attribute__((ext_vector_type(2))) float floatx2;

// ---------------- helpers ----------------
__device__ __forceinline__ unsigned fkey(float f){
    unsigned u = __float_as_uint(f);
    return (u & 0x80000000u) ? ~u : (u | 0x80000000u);
}
__device__ __forceinline__ float funkey(unsigned k){
    unsigned u = (k & 0x80000000u) ? (k ^ 0x80000000u) : ~k;
    return __uint_as_float(u);
}
__device__ __forceinline__ ushort_t f2bf(float f){
    unsigned u = __float_as_uint(f);
    u += 0x7fffu + ((u >> 16) & 1u);      // round-to-nearest-even
    return (ushort_t)(u >> 16);
}
__device__ __forceinline__ float bf2f(ushort_t h){
    return __uint_as_float(((unsigned)h) << 16);
}
__device__ __forceinline__ uchar_t f2fp8(float v){
    int p = __builtin_amdgcn_cvt_pk_fp8_f32(v, v, 0, false);
    return (uchar_t)(p & 0xff);
}
// async global -> LDS, 16B per lane. LDS dest = wave-uniform base + lane*16.
__device__ __forceinline__ void gll16(const void* g, void* l){
    __builtin_amdgcn_global_load_lds(
        (const __attribute__((address_space(1))) unsigned int*)g,
        (__attribute__((address_space(3))) unsigned int*)l, 16, 0, 0);
}
// accumulate 8 fp8 (one int2) into 8 fp32 with weight
__device__ __forceinline__ void acc8f8(float* a, int2 u, float w){
    floatx2 p;
    p = __builtin_amdgcn_cvt_pk_f32_fp8(u.x, false); a[0] += w*p.x; a[1] += w*p.y;
    p = __builtin_amdgcn_cvt_pk_f32_fp8(u.x, true);  a[2] += w*p.x; a[3] += w*p.y;
    p = __builtin_amdgcn_cvt_pk_f32_fp8(u.y, false); a[4] += w*p.x; a[5] += w*p.y;
    p = __builtin_amdgcn_cvt_pk_f32_fp8(u.y, true);  a[6] += w*p.x; a[7] += w*p.y;
}

// ---------------- embeddings (write bf16 states + fp8 shadow) ----------------
__global__ __launch_bounds__(256) void k_embed_place(
    const float* __restrict__ pf, const float* __restrict__ Wpe,
    const float* __restrict__ bpe, ushort_t* __restrict__ out,
    uchar_t* __restrict__ outf8, int P)
{
    int idx = blockIdx.x*256 + threadIdx.x;     // 4-elem group index over P*32
    if (idx >= P*32) return;
    int p = idx >> 5, q = (idx & 31) << 2;
    float v = pf[p];
    float4 w = *(const float4*)(Wpe + q);
    float4 b = *(const float4*)(bpe + q);
    float v0 = v*w.x + b.x, v1 = v*w.y + b.y, v2 = v*w.z + b.z, v3 = v*w.w + b.w;
    ushort4 o;
    o.x = f2bf(v0); o.y = f2bf(v1); o.z = f2bf(v2); o.w = f2bf(v3);
    *(ushort4*)(out + (size_t)p*H + q) = o;
    int pk = __builtin_amdgcn_cvt_pk_fp8_f32(v0, v1, 0, false);
    pk = __builtin_amdgcn_cvt_pk_fp8_f32(v2, v3, pk, true);
    *(int*)(outf8 + (size_t)p*H + q) = pk;
}

__global__ __launch_bounds__(256) void k_embed_trans(
    const float* __restrict__ tf, const float* __restrict__ Wte,
    const float* __restrict__ bte, ushort_t* __restrict__ out,
    uchar_t* __restrict__ outf8, int T)
{
    __shared__ float Wl[8*H];
    __shared__ float Bl[H];
    int tid = threadIdx.x;
    #pragma unroll
    for (int t = 0; t < 4; t++) Wl[tid + t*256] = Wte[tid + t*256];
    if (tid < H) Bl[tid] = bte[tid];
    __syncthreads();
    int idx = blockIdx.x*256 + tid;
    if (idx >= T*32) return;
    int t = idx >> 5, q = (idx & 31) << 2;
    float4 acc = *(float4*)(&Bl[q]);
    #pragma unroll
    for (int k = 0; k < 8; k++){
        float s = tf[(size_t)t*8 + k];
        float4 w = *(float4*)(&Wl[k*H + q]);
        acc.x += s*w.x; acc.y += s*w.y; acc.z += s*w.z; acc.w += s*w.w;
    }
    ushort4 o;
    o.x = f2bf(acc.x); o.y = f2bf(acc.y); o.z = f2bf(acc.z); o.w = f2bf(acc.w);
    *(ushort4*)(out + (size_t)t*H + q) = o;
    int pk = __builtin_amdgcn_cvt_pk_fp8_f32(acc.x, acc.y, 0, false);
    pk = __builtin_amdgcn_cvt_pk_fp8_f32(acc.z, acc.w, pk, true);
    *(int*)(outf8 + (size_t)t*H + q) = pk;
}

// prefix embedding + zero small accumulators + all softmax slots
__global__ void k_init_small(const float* __restrict__ pe, int plen,
                             const float* __restrict__ Wpr, const float* __restrict__ bpr,
                             float* __restrict__ prefix, float* __restrict__ meanP,
                             float* __restrict__ meanT, float* __restrict__ slots)
{
    int c = threadIdx.x;  // 128 threads
    float a = bpr[c];
    for (int k = 0; k < plen; k++) a += pe[k]*Wpr[k*H + c];
    prefix[c] = a;
    meanP[c] = 0.f;
    meanT[c] = 0.f;
    if (c < 16) slots[c] = 0.f;   // fkey-space 0 == -inf; Sp slots start at 0
}

// ---------------- weight convert: A1-half of combined update weights --------
// WT per layer: [side0: tu-combined 128x256][side1: pu-combined 128x256]
// k entries 0..127 (A1/top half) written here; 128..255 (Wc) by k_wfold.
__global__ __launch_bounds__(256) void k_wconv(
    const float* __restrict__ tu_W, const float* __restrict__ pu_W,
    ushort_t* __restrict__ WT, int total)
{
    int e = blockIdx.x*256 + threadIdx.x;
    if (e >= total) return;
    int l = e / 32768, oo = e - l*32768;
    int side = oo >> 14, o2 = oo & 16383;
    int n = o2 >> 7, k = o2 & 127;
    const float* Bm = side ? (pu_W + (size_t)l*32768) : (tu_W + (size_t)l*32768);
    WT[(size_t)l*65536 + (size_t)side*32768 + n*256 + k] = f2bf(Bm[(size_t)k*H + n]);
}

// ---------------- folded Wc GEMM (fp32, one output per thread) ---------------
// Wc[n][k] = sum_j A[k][j] * Bm[128+j][n]; A per-thread rows contiguous,
// Bm reads broadcast across the 128-thread k-run (matrices L2-resident).
__global__ __launch_bounds__(256) void k_wfold(
    const float* __restrict__ p2t_W, const float* __restrict__ t2p_W,
    const float* __restrict__ tu_W,  const float* __restrict__ pu_W,
    ushort_t* __restrict__ WT, int total)   // total = L*32768
{
    int e = blockIdx.x*256 + threadIdx.x;
    if (e >= total) return;
    int l = e / 32768, oo = e - l*32768;
    int side = oo >> 14, o2 = oo & 16383;
    int n = o2 >> 7, k = o2 & 127;
    const float* A  = side ? (t2p_W + (size_t)l*16384) : (p2t_W + (size_t)l*16384);
    const float* Bm = side ? (pu_W  + (size_t)l*32768) : (tu_W  + (size_t)l*32768);
    const float* Ar = A + (size_t)k*H;
    const float* Bc = Bm + (size_t)128*H + n;
    float s = 0.f;
    #pragma unroll 4
    for (int j = 0; j < 128; j++) s += Ar[j] * Bc[(size_t)j*H];
    WT[(size_t)l*65536 + (size_t)side*32768 + n*256 + 128 + k] = f2bf(s);
}

// ---------------- folded small vectors: wv, bc, c0 ---------------------------
__global__ __launch_bounds__(128) void k_wsmall(
    const float* __restrict__ p2t_W, const float* __restrict__ t2p_W,
    const float* __restrict__ tu_W,  const float* __restrict__ pu_W,
    const float* __restrict__ p2t_b, const float* __restrict__ t2p_b,
    const float* __restrict__ ta_W,  const float* __restrict__ ta_b,
    const float* __restrict__ pa_W,  const float* __restrict__ pa_b,
    float* __restrict__ wv, float* __restrict__ c0v, float* __restrict__ bcv)
{
    int b = blockIdx.x, l = b >> 1, side = b & 1;
    const float* A  = side ? (t2p_W + (size_t)l*16384) : (p2t_W + (size_t)l*16384);
    const float* Bm = side ? (pu_W  + (size_t)l*32768) : (tu_W  + (size_t)l*32768);
    const float* ab = side ? (t2p_b + (size_t)l*H) : (p2t_b + (size_t)l*H);
    const float* av = side ? (pa_W  + (size_t)l*H) : (ta_W  + (size_t)l*H);
    float asc       = side ? pa_b[l] : ta_b[l];
    int tid = threadIdx.x;
    int o = (l*2 + side)*H;
    float s = 0.f;
    for (int n = 0; n < 128; n++) s += A[(size_t)tid*H + n] * av[n];
    wv[o + tid] = s;
    float s2 = 0.f;
    for (int j = 0; j < 128; j++) s2 += ab[j] * Bm[(size_t)(128+j)*H + tid];
    bcv[o + tid] = s2;
    if (tid == 0){
        float c = 0.f;
        for (int n = 0; n < 128; n++) c += ab[n]*av[n];
        c0v[l*2 + side] = c + asc;
    }
}

// ---------------- CSR build ----------------
__global__ __launch_bounds__(256) void k_zero_ints(int* __restrict__ p, int n)
{
    int i = blockIdx.x*256 + threadIdx.x;
    int stride = gridDim.x*256;
    for (; i < n; i += stride) p[i] = 0;
}

__global__ __launch_bounds__(256) void k_hist2(
    const int* __restrict__ preD, const int* __restrict__ postD, int E,
    int* __restrict__ cntPre, int* __restrict__ cntPost,
    int* __restrict__ rankPre, int* __restrict__ rankPost)
{
    int i = blockIdx.x*256 + threadIdx.x;
    int stride = gridDim.x*256;
    for (; i < E; i += stride){
        rankPre[i] = atomicAdd(&cntPre[preD[i]], 1);
        rankPost[i] = atomicAdd(&cntPost[postD[i]], 1);
    }
}

__global__ __launch_bounds__(256) void k_scan_part(
    const int* __restrict__ cnt, int N, int* __restrict__ bsum)
{
    __shared__ int wsum[4];
    int tid = threadIdx.x, lane = tid & 63, wid = tid >> 6;
    int base = blockIdx.x*1024 + tid*4;
    int4 v = make_int4(0,0,0,0);
    if (base + 3 < N) v = *(const int4*)(cnt + base);
    else {
        if (base+0 < N) v.x = cnt[base+0];
        if (base+1 < N) v.y = cnt[base+1];
        if (base+2 < N) v.z = cnt[base+2];
    }
    int s = v.x + v.y + v.z + v.w;
    #pragma unroll
    for (int o = 1; o < 64; o <<= 1) s += __shfl_xor(s, o);
    if (lane == 0) wsum[wid] = s;
    __syncthreads();
    if (tid == 0) bsum[blockIdx.x] = wsum[0] + wsum[1] + wsum[2] + wsum[3];
}

__global__ __launch_bounds__(256) void k_scan_bsum(int* __restrict__ bsum, int nb)
{
    __shared__ int wsum[4];
    int tid = threadIdx.x, lane = tid & 63, wid = tid >> 6;
    int x = (tid < nb) ? bsum[tid] : 0;
    int inc = x;
    #pragma unroll
    for (int o = 1; o < 64; o <<= 1){
        int u = __shfl_up(inc, o);
        if (lane >= o) inc += u;
    }
    if (lane == 63) wsum[wid] = inc;
    __syncthreads();
    int woff = 0;
    if (wid > 0) woff += wsum[0];
    if (wid > 1) woff += wsum[1];
    if (wid > 2) woff += wsum[2];
    if (tid < nb) bsum[tid] = woff + inc - x;
}

__global__ __launch_bounds__(256) void k_scan_final(
    const int* __restrict__ cnt, int N, const int* __restrict__ bsum,
    int* __restrict__ rp, int E)
{
    __shared__ int wsum[4];
    int tid = threadIdx.x, lane = tid & 63, wid = tid >> 6;
    int base = blockIdx.x*1024 + tid*4;
    int4 v = make_int4(0,0,0,0);
    if (base + 3 < N) v = *(const int4*)(cnt + base);
    else {
        if (base+0 < N) v.x = cnt[base+0];
        if (base+1 < N) v.y = cnt[base+1];
        if (base+2 < N) v.z = cnt[base+2];
    }
    int t0 = v.x, t1 = t0 + v.y, t2 = t1 + v.z, t3 = t2 + v.w;
    int inc = t3;
    #pragma unroll
    for (int o = 1; o < 64; o <<= 1){
        int u = __shfl_up(inc, o);
        if (lane >= o) inc += u;
    }
    if (lane == 63) wsum[wid] = inc;
    __syncthreads();
    int woff = 0;
    if (wid > 0) woff += wsum[0];
    if (wid > 1) woff += wsum[1];
    if (wid > 2) woff += wsum[2];
    int off = bsum[blockIdx.x] + woff + inc - t3;
    if (base+0 < N) rp[base+0] = off;
    if (base+1 < N) rp[base+1] = off + t0;
    if (base+2 < N) rp[base+2] = off + t1;
    if (base+3 < N) rp[base+3] = off + t2;
    if (blockIdx.x == 0 && tid == 0) rp[N] = E;
}

__global__ __launch_bounds__(256) void k_fill2(
    const int* __restrict__ preS, const int* __restrict__ preD,
    const int* __restrict__ postS, const int* __restrict__ postD, int E,
    const int* __restrict__ rpPre, const int* __restrict__ rankPre, int* __restrict__ csrPre,
    const int* __restrict__ rpPost, const int* __restrict__ rankPost, int* __restrict__ csrPost)
{
    int i = blockIdx.x*256 + threadIdx.x;
    int stride = gridDim.x*256;
    for (; i < E; i += stride){
        csrPre[rpPre[preD[i]] + rankPre[i]] = preS[i];
        csrPost[rpPost[postD[i]] + rankPost[i]] = postS[i];
    }
}

// ---------------- score GEMV: y[r] = h[r].wv + c0, fused global max ----------
__global__ __launch_bounds__(256) void k_gemv(
    const ushort_t* __restrict__ A, int M,
    const float* __restrict__ wv, const float* __restrict__ c0v, int c0i,
    float* __restrict__ y, unsigned* __restrict__ Mkey)
{
    __shared__ float wm[4];
    int tid = threadIdx.x, lane = tid & 63, wid = tid >> 6;
    int g = tid >> 4, gl = tid & 15;
    float w8[8];
    #pragma unroll
    for (int i = 0; i < 8; i++) w8[i] = wv[gl*8 + i];
    float c0 = c0v[c0i];
    int stride = gridDim.x*16;
    float lmax = -3.402823466e38f;
    for (int r = blockIdx.x*16 + g; r < M; r += stride){
        short8 u = *(const short8*)(A + (size_t)r*H + gl*8);
        float s = 0.f;
        #pragma unroll
        for (int i = 0; i < 8; i++) s += bf2f((ushort_t)u[i]) * w8[i];
        s += __shfl_xor(s, 1); s += __shfl_xor(s, 2);
        s += __shfl_xor(s, 4); s += __shfl_xor(s, 8);
        s += c0;
        if (gl == 0) y[r] = s;
        lmax = fmaxf(lmax, s);
    }
    #pragma unroll
    for (int o = 1; o < 64; o <<= 1) lmax = fmaxf(lmax, __shfl_xor(lmax, o));
    if (lane == 0) wm[wid] = lmax;
    __syncthreads();
    if (tid == 0){
        float m = fmaxf(fmaxf(wm[0], wm[1]), fmaxf(wm[2], wm[3]));
        atomicMax(Mkey, fkey(m));
    }
}

// ---------------- softmax denominator over edge src list --------------------
__global__ __launch_bounds__(256) void k_sumexp(
    const int* __restrict__ src, int E, const float* __restrict__ y,
    const unsigned* __restrict__ Mkey, float* __restrict__ Sp)
{
    __shared__ float red[4];
    int tid = threadIdx.x, lane = tid & 63, wid = tid >> 6;
    int gid = blockIdx.x*256 + tid, stride = gridDim.x*256;
    float Mv = funkey(Mkey[0]);
    float ls = 0.f;
    for (int e = gid; e < E; e += stride) ls += expf(y[src[e]] - Mv);
    #pragma unroll
    for (int o = 1; o < 64; o <<= 1) ls += __shfl_xor(ls, o);
    if (lane == 0) red[wid] = ls;
    __syncthreads();
    if (tid == 0) atomicAdd(Sp, red[0] + red[1] + red[2] + red[3]);
}

// ---------------- CSR gather of fp8 shadow state rows + sdeg -----------------
// G[r] = sum_e exp(y[src]-M) * X[src]  (UNNORMALIZED),  sdeg[r] = sum exp.
__global__ __launch_bounds__(256) void k_gatherH(
    const int* __restrict__ rp, const int* __restrict__ csr, int Nrow,
    const float* __restrict__ y, const uchar_t* __restrict__ X,
    ushort_t* __restrict__ G, float* __restrict__ sdeg,
    const unsigned* __restrict__ Mkey)
{
    int tid = threadIdx.x;
    int g = tid >> 4, gl = tid & 15;          // 16 groups x 16 lanes
    int r = blockIdx.x*16 + g;
    if (r >= Nrow) return;
    float Mv = funkey(Mkey[0]);
    int j0 = rp[r], j1 = rp[r+1];
    const int2* X8 = (const int2*)X;          // fp8 row = 16 int2 (128 fp8)
    float a[8] = {0.f,0.f,0.f,0.f,0.f,0.f,0.f,0.f};
    float se = 0.f;
    int j = j0;
    for (; j + 1 < j1; j += 2){
        int s0 = csr[j], s1 = csr[j+1];
        float e0 = expf(y[s0] - Mv);
        float e1 = expf(y[s1] - Mv);
        int2 u0 = X8[(size_t)s0*16 + gl];
        int2 u1 = X8[(size_t)s1*16 + gl];
        se += e0 + e1;
        acc8f8(a, u0, e0);
        acc8f8(a, u1, e1);
    }
    if (j < j1){
        int s0 = csr[j];
        float e0 = expf(y[s0] - Mv);
        int2 u0 = X8[(size_t)s0*16 + gl];
        se += e0;
        acc8f8(a, u0, e0);
    }
    int4 o;
    o.x = (int)((((unsigned)f2bf(a[1])) << 16) | (unsigned)f2bf(a[0]));
    o.y = (int)((((unsigned)f2bf(a[3])) << 16) | (unsigned)f2bf(a[2]));
    o.z = (int)((((unsigned)f2bf(a[5])) << 16) | (unsigned)f2bf(a[4]));
    o.w = (int)((((unsigned)f2bf(a[7])) << 16) | (unsigned)f2bf(a[6]));
    ((int4*)G)[(size_t)r*16 + gl] = o;
    if (gl == 0) sdeg[r] = se;
}

// ---------------- update GEMM ------------------------------------------------
// out = relu(A1 + A1@Wtop + invS*(G@Wc + sdeg*bc) + b)   [IN-PLACE: out == A1]
// 3-buffer LDS ring (2-deep prefetch, counted vmcnt, raw s_barrier), XOR-
// swizzled via pre-swizzled global source. Residual A1 via identity-MFMA.
// Also emits fp8 shadow of out. In-place is safe: each row is staged before
// its store, rows are block-disjoint, asm memory clobbers pin op order.
// REQUIRES M % 16 == 0 handled by generic tail (vmcnt(0)) otherwise.
__global__ __launch_bounds__(256, 4) void k_gemm_up(
    const ushort_t* A1, const ushort_t* __restrict__ A2,
    const ushort_t* __restrict__ WT, const float* __restrict__ bias,
    const float* __restrict__ bcp, const float* __restrict__ Sp,
    const float* __restrict__ sdeg,
    ushort_t* out, uchar_t* __restrict__ outF8, int M,
    float* __restrict__ colsum)
{
    __shared__ __align__(16) char As[3*8192];   // 3 x (A1 4KB | A2 4KB)
    __shared__ float csum[H];
    int tid = threadIdx.x;
    int lane = tid & 63, wid = tid >> 6;
    int quad = lane >> 4, l15 = lane & 15;
    int strip = wid*32;
    short8 bfr1[2][4], bfr2[2][4];
    float bcol[2], bc2[2];
    #pragma unroll
    for (int j = 0; j < 2; j++){
        int col = strip + j*16 + l15;
        #pragma unroll
        for (int kk = 0; kk < 4; kk++){
            bfr1[j][kk] = *(const short8*)(WT + (size_t)col*256 + kk*32 + quad*8);
            bfr2[j][kk] = *(const short8*)(WT + (size_t)col*256 + 128 + kk*32 + quad*8);
        }
        bcol[j] = bias[col];
        bc2[j]  = bcp[col];
    }
    // identity B-fragments: transpose the wave's A1 fragment window into C-layout
    short8 If0, If1;
    #pragma unroll
    for (int e = 0; e < 8; e++){
        int kloc = quad*8 + e;
        If0[e] = (kloc == l15)      ? (short)0x3F80 : (short)0;
        If1[e] = (kloc == l15 + 16) ? (short)0x3F80 : (short)0;
    }
    float invS = 1.f / Sp[0];
    const bool has_cs = (colsum != nullptr);
    if (has_cs && tid < H) csum[tid] = 0.f;
    float cs[2] = {0.f, 0.f};

    int tiles = (M + 15) >> 4;
    int G = gridDim.x;
    int t0 = blockIdx.x;
    if (t0 >= tiles) return;
    int srow = tid >> 4;
    int su = (tid & 15) ^ srow;
    const ushort_t* g1b = A1 + (size_t)srow*H + su*8;
    const ushort_t* g2b = A2 + (size_t)srow*H + su*8;
    char* AsB = As;

    #define STAGE_UP(bo, t) do { \
        gll16(g1b + (size_t)(t)*(16*H), AsB + (bo) + (wid<<10)); \
        gll16(g2b + (size_t)(t)*(16*H), AsB + (bo) + 4096 + (wid<<10)); \
    } while(0)

    STAGE_UP(0, t0);
    int t1p = t0 + G;
    if (t1p < tiles){
        STAGE_UP(8192, t1p);
        asm volatile("s_waitcnt vmcnt(2)\ns_barrier" ::: "memory");
    } else {
        asm volatile("s_waitcnt vmcnt(0)\ns_barrier" ::: "memory");
    }

    int t = t0, bo = 0;
    for (;;){
        const char* rb = AsB + bo;
        int row0 = t << 4;
        float4 sd4 = *(const float4*)(sdeg + row0 + quad*4);
        float sdv[4] = {sd4.x, sd4.y, sd4.z, sd4.w};
        short8 a1f[4], a2f[4];
        #pragma unroll
        for (int kk = 0; kk < 4; kk++){
            int sw = ((((kk<<2)+quad) ^ l15) << 4);
            a1f[kk] = *(const short8*)(rb + (l15<<8) + sw);
            a2f[kk] = *(const short8*)(rb + 4096 + (l15<<8) + sw);
        }
        short8 ares = *(const short8*)(rb + (l15<<8) + ((((wid<<2)+quad) ^ l15) << 4));
        floatx4 acc1[2], acc2[2];
        acc1[0] = __builtin_amdgcn_mfma_f32_16x16x32_bf16(ares, If0, (floatx4)0.f, 0,0,0);
        acc1[1] = __builtin_amdgcn_mfma_f32_16x16x32_bf16(ares, If1, (floatx4)0.f, 0,0,0);
        acc2[0] = (floatx4)0.f; acc2[1] = (floatx4)0.f;
        #pragma unroll
        for (int j = 0; j < 2; j++){
            #pragma unroll
            for (int kk = 0; kk < 4; kk++)
                acc1[j] = __builtin_amdgcn_mfma_f32_16x16x32_bf16(a1f[kk], bfr1[j][kk], acc1[j], 0,0,0);
            #pragma unroll
            for (int kk = 0; kk < 4; kk++)
                acc2[j] = __builtin_amdgcn_mfma_f32_16x16x32_bf16(a2f[kk], bfr2[j][kk], acc2[j], 0,0,0);
        }
        #pragma unroll
        for (int j = 0; j < 2; j++){
            int col = strip + j*16 + l15;
            #pragma unroll
            for (int rr = 0; rr < 4; rr++){
                int grow = row0 + quad*4 + rr;
                float v = acc1[j][rr] + invS*(acc2[j][rr] + sdv[rr]*bc2[j]) + bcol[j];
                v = fmaxf(v, 0.f);
                out[(size_t)grow*H + col] = f2bf(v);       // 8 ushort stores
                outF8[(size_t)grow*H + col] = f2fp8(v);    // 8 byte stores
                if (has_cs) cs[j] += v;
            }
        }
        int tn = t + G;
        if (tn >= tiles) break;
        int tnn = tn + G;
        int bo2 = bo + 8192; if (bo2 >= 24576) bo2 = 0;
        int bo3 = bo2 + 8192; if (bo3 >= 24576) bo3 = 0;
        // wait for stage(tn): ops newer = 1 sdeg + 16 stores (+2 stage if issued)
        if (tnn < tiles){
            STAGE_UP(bo3, tnn);
            asm volatile("s_waitcnt vmcnt(19)\ns_barrier" ::: "memory");
        } else {
            asm volatile("s_waitcnt vmcnt(17)\ns_barrier" ::: "memory");
        }
        t = tn; bo = bo2;
    }
    #undef STAGE_UP
    if (has_cs){
        #pragma unroll
        for (int j = 0; j < 2; j++){
            float v = cs[j];
            v += __shfl_xor(v, 16); v += __shfl_xor(v, 32);
            if (quad == 0) atomicAdd(&csum[strip + j*16 + l15], v);
        }
        __syncthreads();
        if (tid < H) atomicAdd(&colsum[tid], csum[tid]);
    }
}

// ---------------- tiny MLP head ----------------
__global__ __launch_bounds__(256) void k_head(
    const float* __restrict__ meanP, const float* __restrict__ meanT,
    float invP, float invT,
    const float* __restrict__ Wpp, const float* __restrict__ bpp,
    const float* __restrict__ Wtp, const float* __restrict__ btp,
    const float* __restrict__ prefix,
    const float* __restrict__ W1, const float* __restrict__ b1,
    const float* __restrict__ W2, const float* __restrict__ b2,
    float* __restrict__ h2g)
{
    __shared__ float comb[384];
    __shared__ float h1s[256];
    int tid = threadIdx.x;
    if (tid < 128){
        float a = bpp[tid];
        for (int k = 0; k < 128; k++) a += meanP[k]*invP*Wpp[k*H + tid];
        comb[tid] = a;
        comb[256 + tid] = prefix[tid];
    } else {
        int c = tid - 128;
        float a = btp[c];
        for (int k = 0; k < 128; k++) a += meanT[k]*invT*Wtp[k*H + c];
        comb[128 + c] = a;
    }
    __syncthreads();
    {
        float a = b1[tid];
        for (int k = 0; k < 384; k++) a += comb[k]*W1[k*256 + tid];
        h1s[tid] = fmaxf(a, 0.f);
    }
    __syncthreads();
    if (tid < 128){
        float a = b2[tid];
        for (int k = 0; k < 256; k++) a += h1s[k]*W2[k*H + tid];
        h2g[tid] = fmaxf(a, 0.f);
    }
}

// ---------------- logits + sigmoid ----------------
__global__ __launch_bounds__(256) void k_logits(
    const float* __restrict__ h2g, const float* __restrict__ W3,
    const float* __restrict__ b3, float* __restrict__ out, int T)
{
    __shared__ float h2l[128];
    int tid = threadIdx.x;
    if (tid < 128) h2l[tid] = h2g[tid];
    __syncthreads();
    int t = blockIdx.x*256 + tid;
    if (t >= T) return;
    float a = b3[t];
    #pragma unroll 8
    for (int k = 0; k < 128; k++) a += h2l[k]*W3[(size_t)k*T + t];
    out[t] = 1.f/(1.f + expf(-a));
}

// ---------------- launch ----------------
extern "C" void kernel_launch(void* const* d_in, const int* in_sizes, int n_in,
                              void* d_out, int out_size, void* d_ws, size_t ws_size,
                              hipStream_t stream)
{
    (void)n_in; (void)out_size; (void)ws_size;
    const float* pf    = (const float*)d_in[0];
    const float* tf    = (const float*)d_in[1];
    const float* pe    = (const float*)d_in[2];
    const int*   pre   = (const int*)d_in[3];
    const int*   post  = (const int*)d_in[4];
    const float* W_pe  = (const float*)d_in[5];
    const float* b_pe  = (const float*)d_in[6];
    const float* W_te  = (const float*)d_in[7];
    const float* b_te  = (const float*)d_in[8];
    const float* W_pr  = (const float*)d_in[9];
    const float* b_pr  = (const float*)d_in[10];
    const float* p2t_W = (const float*)d_in[11];
    const float* p2t_b = (const float*)d_in[12];
    const float* t2p_W = (const float*)d_in[13];
    const float* t2p_b = (const float*)d_in[14];
    const float* pu_W  = (const float*)d_in[15];
    const float* pu_b  = (const float*)d_in[16];
    const float* tu_W  = (const float*)d_in[17];
    const float* tu_b  = (const float*)d_in[18];
    const float* pa_W  = (const float*)d_in[19];
    const float* pa_b  = (const float*)d_in[20];
    const float* ta_W  = (const float*)d_in[21];
    const float* ta_b  = (const float*)d_in[22];
    const float* W_pp  = (const float*)d_in[23];
    const float* b_pp  = (const float*)d_in[24];
    const float* W_tp  = (const float*)d_in[25];
    const float* b_tp  = (const float*)d_in[26];
    const float* W1    = (const float*)d_in[27];
    const float* b1    = (const float*)d_in[28];
    const float* W2    = (const float*)d_in[29];
    const float* b2    = (const float*)d_in[30];
    const float* W3    = (const float*)d_in[31];
    const float* b3    = (const float*)d_in[32];

    int P = in_sizes[0];
    int T = in_sizes[1] / 8;
    int E = in_sizes[3] / 2;
    int plen = in_sizes[2];
    int L = in_sizes[11] / (H*H);

    float* ws = (float*)d_ws;
    size_t fP = (size_t)P*H, fT = (size_t)T*H;
    size_t fN = (fP > fT) ? fP : fT;
    int   Nmax = (P > T) ? P : T;

    float* yb    = ws;                    // [Nmax] fp32 scores
    float* sdegA = yb + Nmax;             // [Nmax] per-trans sum of exp (pre side)
    float* sdegB = sdegA + Nmax;          // [Nmax] per-place sum of exp (post side)
    float* sc    = sdegB + Nmax;          // 16 softmax slots
    float* meanP   = sc + 16;
    float* meanT   = sc + 144;
    float* prefix  = sc + 272;
    float* h2g     = sc + 400;            // end at sc+544
    float* wvv  = sc + 544;               // [L*2*128] folded score vectors
    float* c0v  = wvv + (size_t)L*256;    // [32] folded score consts (padded)
    float* bcv  = c0v + 32;               // [L*2*128] folded bias rows

    ushort_t* bh = (ushort_t*)(bcv + (size_t)L*256);
    ushort_t* place_h = bh;               // [P,128] bf16 (updated IN-PLACE)
    ushort_t* trans_h = place_h + fP;     // [T,128] bf16 (updated IN-PLACE)
    ushort_t* GbA     = trans_h + fT;     // [Nmax,128] gathered places (per trans)
    ushort_t* GbB     = GbA + fN;         // [Nmax,128] gathered transes (per place)
    ushort_t* WTb     = GbB + fN;         // L*65536 bf16 combined update weights
    uchar_t*  XP      = (uchar_t*)(WTb + (size_t)L*65536);  // [P,128] fp8 shadow
    uchar_t*  XT      = XP + fP;                             // [T,128] fp8 shadow

    int* iw = (int*)(XT + fT);
    int* cntPre  = iw;                 // [T]
    int* cntPost = cntPre + T;         // [P]
    int* rpPre   = cntPost + P;        // [T+1]
    int* rpPost  = rpPre + (T + 1);    // [P+1]
    int* csrPre  = rpPost + (P + 2);   // [E]
    int* csrPost = csrPre + E;         // [E]
    int* rankPre = csrPost + E;        // [E]
    int* rankPost= rankPre + E;        // [E]
    int* bsumA   = rankPost + E;       // [256]
    int* bsumB   = bsumA + 256;        // [256]

    const int* pre_src  = pre;          const int* pre_dst  = pre + E;
    const int* post_src = post;         const int* post_dst = post + E;

    int wtot = L*32768;
    int nbT = (T + 1023)/1024, nbP = (P + 1023)/1024;

    // update-GEMM grids: ring, 5 tiles/block
    int tilesP = (P + 15) >> 4, tilesT = (T + 15) >> 4;
    int gridP = (tilesP + 4)/5, gridT = (tilesT + 4)/5;

    k_init_small<<<1, 128, 0, stream>>>(pe, plen, W_pr, b_pr, prefix, meanP, meanT, sc);
    k_wconv<<<(wtot + 255)/256, 256, 0, stream>>>(tu_W, pu_W, WTb, wtot);
    k_wfold<<<(wtot + 255)/256, 256, 0, stream>>>(p2t_W, t2p_W, tu_W, pu_W, WTb, wtot);
    k_wsmall<<<L*2, 128, 0, stream>>>(p2t_W, t2p_W, tu_W, pu_W, p2t_b, t2p_b,
                                      ta_W, ta_b, pa_W, pa_b, wvv, c0v, bcv);
    k_zero_ints<<<256, 256, 0, stream>>>(iw, P + T);
    k_hist2<<<2048, 256, 0, stream>>>(pre_dst, post_dst, E,
                                      cntPre, cntPost, rankPre, rankPost);
    k_scan_part<<<nbT, 256, 0, stream>>>(cntPre, T, bsumA);
    k_scan_bsum<<<1, 256, 0, stream>>>(bsumA, nbT);
    k_scan_final<<<nbT, 256, 0, stream>>>(cntPre, T, bsumA, rpPre, E);
    k_scan_part<<<nbP, 256, 0, stream>>>(cntPost, P, bsumB);
    k_scan_bsum<<<1, 256, 0, stream>>>(bsumB, nbP);
    k_scan_final<<<nbP, 256, 0, stream>>>(cntPost, P, bsumB, rpPost, E);
    k_fill2<<<1024, 256, 0, stream>>>(pre_src, pre_dst, post_src, post_dst, E,
                                      rpPre, rankPre, csrPre,
                                      rpPost, rankPost, csrPost);

    k_embed_place<<<(P*32 + 255)/256, 256, 0, stream>>>(pf, W_pe, b_pe, place_h, XP, P);
    k_embed_trans<<<(T*32 + 255)/256, 256, 0, stream>>>(tf, W_te, b_te, trans_h, XT, T);

    for (int l = 0; l < L; l++){
        const ushort_t* tuT = WTb + (size_t)l*65536;           // side 0
        const ushort_t* puT = tuT + 32768;                     // side 1
        const float* pub  = pu_b  + (size_t)l*H;
        const float* tub  = tu_b  + (size_t)l*H;
        const float* wvA  = wvv + (size_t)(l*2 + 0)*H;
        const float* wvB  = wvv + (size_t)(l*2 + 1)*H;
        const float* bcA  = bcv + (size_t)(l*2 + 0)*H;
        const float* bcB  = bcv + (size_t)(l*2 + 1)*H;
        unsigned* MkA = (unsigned*)(sc + l*4 + 0);   float* SpA = sc + l*4 + 1;
        unsigned* MkB = (unsigned*)(sc + l*4 + 2);   float* SpB = sc + l*4 + 3;
        int last = (l == L-1);

        // ALL reads of layer-start states happen before the in-place updates.
        // phase A: place scores -> stats -> gather places into GbA (per trans)
        k_gemv<<<512, 256, 0, stream>>>(place_h, P, wvA, c0v, l*2 + 0, yb, MkA);
        k_sumexp<<<256, 256, 0, stream>>>(pre_src, E, yb, MkA, SpA);
        k_gatherH<<<(T + 15)/16, 256, 0, stream>>>(rpPre, csrPre, T, yb, XP,
                                                   GbA, sdegA, MkA);
        // phase B: trans scores -> stats -> gather transes into GbB (per place)
        k_gemv<<<512, 256, 0, stream>>>(trans_h, T, wvB, c0v, l*2 + 1, yb, MkB);
        k_sumexp<<<256, 256, 0, stream>>>(post_src, E, yb, MkB, SpB);
        k_gatherH<<<(P + 15)/16, 256, 0, stream>>>(rpPost, csrPost, P, yb, XT,
                                                   GbB, sdegB, MkB);

        // in-place updates (+ fp8 shadow refresh)
        k_gemm_up<<<gridT, 256, 0, stream>>>(trans_h, GbA, tuT, tub, bcA, SpA,
                                             sdegA, trans_h, XT, T,
                                             last ? meanT : nullptr);
        k_gemm_up<<<gridP, 256, 0, stream>>>(place_h, GbB, puT, pub, bcB, SpB,
                                             sdegB, place_h, XP, P,
                                             last ? meanP : nullptr);
    }

    k_head<<<1, 256, 0, stream>>>(meanP, meanT, 1.f/(float)P, 1.f/(float)T,
                                  W_pp, b_pp, W_tp, b_tp, prefix, W1, b1, W2, b2, h2g);
    k_logits<<<(T + 255)/256, 256, 0, stream>>>(h2g, W3, b3, (float*)d_out, T);
}

// Round 6
// 684.283 us; speedup vs baseline: 1.2548x; 1.1269x over previous
//
#include <hip/hip_runtime.h>
#include <cstddef>

#define H 128

typedef unsigned short ushort_t;
typedef unsigned char uchar_t;
typedef __attribute__((ext_vector_type(8))) short short8;
typedef __attribute__((ext_vector_type(4))) float floatx4;
typedef __attribute__((ext_vector_type(2))) float floatx2;

// ---------------- helpers ----------------
__device__ __forceinline__ unsigned fkey(float f){
    unsigned u = __float_as_uint(f);
    return (u & 0x80000000u) ? ~u : (u | 0x80000000u);
}
__device__ __forceinline__ float funkey(unsigned k){
    unsigned u = (k & 0x80000000u) ? (k ^ 0x80000000u) : ~k;
    return __uint_as_float(u);
}
__device__ __forceinline__ ushort_t f2bf(float f){
    unsigned u = __float_as_uint(f);
    u += 0x7fffu + ((u >> 16) & 1u);      // round-to-nearest-even
    return (ushort_t)(u >> 16);
}
__device__ __forceinline__ float bf2f(ushort_t h){
    return __uint_as_float(((unsigned)h) << 16);
}
__device__ __forceinline__ uchar_t f2fp8(float v){
    int p = __builtin_amdgcn_cvt_pk_fp8_f32(v, v, 0, false);
    return (uchar_t)(p & 0xff);
}
// async global -> LDS, 16B per lane. LDS dest = wave-uniform base + lane*16.
__device__ __forceinline__ void gll16(const void* g, void* l){
    __builtin_amdgcn_global_load_lds(
        (const __attribute__((address_space(1))) unsigned int*)g,
        (__attribute__((address_space(3))) unsigned int*)l, 16, 0, 0);
}
// accumulate 8 fp8 (one int2) into 8 fp32 with weight
__device__ __forceinline__ void acc8f8(float* a, int2 u, float w){
    floatx2 p;
    p = __builtin_amdgcn_cvt_pk_f32_fp8(u.x, false); a[0] += w*p.x; a[1] += w*p.y;
    p = __builtin_amdgcn_cvt_pk_f32_fp8(u.x, true);  a[2] += w*p.x; a[3] += w*p.y;
    p = __builtin_amdgcn_cvt_pk_f32_fp8(u.y, false); a[4] += w*p.x; a[5] += w*p.y;
    p = __builtin_amdgcn_cvt_pk_f32_fp8(u.y, true);  a[6] += w*p.x; a[7] += w*p.y;
}

// ---------------- embeddings (write bf16 states + fp8 shadow) ----------------
__global__ __launch_bounds__(256) void k_embed_place(
    const float* __restrict__ pf, const float* __restrict__ Wpe,
    const float* __restrict__ bpe, ushort_t* __restrict__ out,
    uchar_t* __restrict__ outf8, int P)
{
    int idx = blockIdx.x*256 + threadIdx.x;     // 4-elem group index over P*32
    if (idx >= P*32) return;
    int p = idx >> 5, q = (idx & 31) << 2;
    float v = pf[p];
    float4 w = *(const float4*)(Wpe + q);
    float4 b = *(const float4*)(bpe + q);
    float v0 = v*w.x + b.x, v1 = v*w.y + b.y, v2 = v*w.z + b.z, v3 = v*w.w + b.w;
    ushort4 o;
    o.x = f2bf(v0); o.y = f2bf(v1); o.z = f2bf(v2); o.w = f2bf(v3);
    *(ushort4*)(out + (size_t)p*H + q) = o;
    int pk = __builtin_amdgcn_cvt_pk_fp8_f32(v0, v1, 0, false);
    pk = __builtin_amdgcn_cvt_pk_fp8_f32(v2, v3, pk, true);
    *(int*)(outf8 + (size_t)p*H + q) = pk;
}

__global__ __launch_bounds__(256) void k_embed_trans(
    const float* __restrict__ tf, const float* __restrict__ Wte,
    const float* __restrict__ bte, ushort_t* __restrict__ out,
    uchar_t* __restrict__ outf8, int T)
{
    __shared__ float Wl[8*H];
    __shared__ float Bl[H];
    int tid = threadIdx.x;
    #pragma unroll
    for (int t = 0; t < 4; t++) Wl[tid + t*256] = Wte[tid + t*256];
    if (tid < H) Bl[tid] = bte[tid];
    __syncthreads();
    int idx = blockIdx.x*256 + tid;
    if (idx >= T*32) return;
    int t = idx >> 5, q = (idx & 31) << 2;
    float4 acc = *(float4*)(&Bl[q]);
    #pragma unroll
    for (int k = 0; k < 8; k++){
        float s = tf[(size_t)t*8 + k];
        float4 w = *(float4*)(&Wl[k*H + q]);
        acc.x += s*w.x; acc.y += s*w.y; acc.z += s*w.z; acc.w += s*w.w;
    }
    ushort4 o;
    o.x = f2bf(acc.x); o.y = f2bf(acc.y); o.z = f2bf(acc.z); o.w = f2bf(acc.w);
    *(ushort4*)(out + (size_t)t*H + q) = o;
    int pk = __builtin_amdgcn_cvt_pk_fp8_f32(acc.x, acc.y, 0, false);
    pk = __builtin_amdgcn_cvt_pk_fp8_f32(acc.z, acc.w, pk, true);
    *(int*)(outf8 + (size_t)t*H + q) = pk;
}

// prefix embedding + zero small accumulators + all softmax slots
__global__ void k_init_small(const float* __restrict__ pe, int plen,
                             const float* __restrict__ Wpr, const float* __restrict__ bpr,
                             float* __restrict__ prefix, float* __restrict__ meanP,
                             float* __restrict__ meanT, float* __restrict__ slots)
{
    int c = threadIdx.x;  // 128 threads
    float a = bpr[c];
    for (int k = 0; k < plen; k++) a += pe[k]*Wpr[k*H + c];
    prefix[c] = a;
    meanP[c] = 0.f;
    meanT[c] = 0.f;
    if (c < 16) slots[c] = 0.f;   // fkey-space 0 == -inf; Sp slots start at 0
}

// ---------------- weight convert: A1-half of combined update weights --------
__global__ __launch_bounds__(256) void k_wconv(
    const float* __restrict__ tu_W, const float* __restrict__ pu_W,
    ushort_t* __restrict__ WT, int total)
{
    int e = blockIdx.x*256 + threadIdx.x;
    if (e >= total) return;
    int l = e / 32768, oo = e - l*32768;
    int side = oo >> 14, o2 = oo & 16383;
    int n = o2 >> 7, k = o2 & 127;
    const float* Bm = side ? (pu_W + (size_t)l*32768) : (tu_W + (size_t)l*32768);
    WT[(size_t)l*65536 + (size_t)side*32768 + n*256 + k] = f2bf(Bm[(size_t)k*H + n]);
}

// ---------------- folded Wc GEMM (fp32, one output per thread) ---------------
__global__ __launch_bounds__(256) void k_wfold(
    const float* __restrict__ p2t_W, const float* __restrict__ t2p_W,
    const float* __restrict__ tu_W,  const float* __restrict__ pu_W,
    ushort_t* __restrict__ WT, int total)   // total = L*32768
{
    int e = blockIdx.x*256 + threadIdx.x;
    if (e >= total) return;
    int l = e / 32768, oo = e - l*32768;
    int side = oo >> 14, o2 = oo & 16383;
    int n = o2 >> 7, k = o2 & 127;
    const float* A  = side ? (t2p_W + (size_t)l*16384) : (p2t_W + (size_t)l*16384);
    const float* Bm = side ? (pu_W  + (size_t)l*32768) : (tu_W  + (size_t)l*32768);
    const float* Ar = A + (size_t)k*H;
    const float* Bc = Bm + (size_t)128*H + n;
    float s = 0.f;
    #pragma unroll 4
    for (int j = 0; j < 128; j++) s += Ar[j] * Bc[(size_t)j*H];
    WT[(size_t)l*65536 + (size_t)side*32768 + n*256 + 128 + k] = f2bf(s);
}

// ---------------- folded small vectors: wv, bc, c0 ---------------------------
__global__ __launch_bounds__(128) void k_wsmall(
    const float* __restrict__ p2t_W, const float* __restrict__ t2p_W,
    const float* __restrict__ tu_W,  const float* __restrict__ pu_W,
    const float* __restrict__ p2t_b, const float* __restrict__ t2p_b,
    const float* __restrict__ ta_W,  const float* __restrict__ ta_b,
    const float* __restrict__ pa_W,  const float* __restrict__ pa_b,
    float* __restrict__ wv, float* __restrict__ c0v, float* __restrict__ bcv)
{
    int b = blockIdx.x, l = b >> 1, side = b & 1;
    const float* A  = side ? (t2p_W + (size_t)l*16384) : (p2t_W + (size_t)l*16384);
    const float* Bm = side ? (pu_W  + (size_t)l*32768) : (tu_W  + (size_t)l*32768);
    const float* ab = side ? (t2p_b + (size_t)l*H) : (p2t_b + (size_t)l*H);
    const float* av = side ? (pa_W  + (size_t)l*H) : (ta_W  + (size_t)l*H);
    float asc       = side ? pa_b[l] : ta_b[l];
    int tid = threadIdx.x;
    int o = (l*2 + side)*H;
    float s = 0.f;
    for (int n = 0; n < 128; n++) s += A[(size_t)tid*H + n] * av[n];
    wv[o + tid] = s;
    float s2 = 0.f;
    for (int j = 0; j < 128; j++) s2 += ab[j] * Bm[(size_t)(128+j)*H + tid];
    bcv[o + tid] = s2;
    if (tid == 0){
        float c = 0.f;
        for (int n = 0; n < 128; n++) c += ab[n]*av[n];
        c0v[l*2 + side] = c + asc;
    }
}

// ---------------- CSR build ----------------
__global__ __launch_bounds__(256) void k_zero_ints(int* __restrict__ p, int n)
{
    int i = blockIdx.x*256 + threadIdx.x;
    int stride = gridDim.x*256;
    for (; i < n; i += stride) p[i] = 0;
}

__global__ __launch_bounds__(256) void k_hist2(
    const int* __restrict__ preD, const int* __restrict__ postD, int E,
    int* __restrict__ cntPre, int* __restrict__ cntPost,
    int* __restrict__ rankPre, int* __restrict__ rankPost)
{
    int i = blockIdx.x*256 + threadIdx.x;
    int stride = gridDim.x*256;
    for (; i < E; i += stride){
        rankPre[i] = atomicAdd(&cntPre[preD[i]], 1);
        rankPost[i] = atomicAdd(&cntPost[postD[i]], 1);
    }
}

__global__ __launch_bounds__(256) void k_scan_part(
    const int* __restrict__ cnt, int N, int* __restrict__ bsum)
{
    __shared__ int wsum[4];
    int tid = threadIdx.x, lane = tid & 63, wid = tid >> 6;
    int base = blockIdx.x*1024 + tid*4;
    int4 v = make_int4(0,0,0,0);
    if (base + 3 < N) v = *(const int4*)(cnt + base);
    else {
        if (base+0 < N) v.x = cnt[base+0];
        if (base+1 < N) v.y = cnt[base+1];
        if (base+2 < N) v.z = cnt[base+2];
    }
    int s = v.x + v.y + v.z + v.w;
    #pragma unroll
    for (int o = 1; o < 64; o <<= 1) s += __shfl_xor(s, o);
    if (lane == 0) wsum[wid] = s;
    __syncthreads();
    if (tid == 0) bsum[blockIdx.x] = wsum[0] + wsum[1] + wsum[2] + wsum[3];
}

__global__ __launch_bounds__(256) void k_scan_bsum(int* __restrict__ bsum, int nb)
{
    __shared__ int wsum[4];
    int tid = threadIdx.x, lane = tid & 63, wid = tid >> 6;
    int x = (tid < nb) ? bsum[tid] : 0;
    int inc = x;
    #pragma unroll
    for (int o = 1; o < 64; o <<= 1){
        int u = __shfl_up(inc, o);
        if (lane >= o) inc += u;
    }
    if (lane == 63) wsum[wid] = inc;
    __syncthreads();
    int woff = 0;
    if (wid > 0) woff += wsum[0];
    if (wid > 1) woff += wsum[1];
    if (wid > 2) woff += wsum[2];
    if (tid < nb) bsum[tid] = woff + inc - x;
}

__global__ __launch_bounds__(256) void k_scan_final(
    const int* __restrict__ cnt, int N, const int* __restrict__ bsum,
    int* __restrict__ rp, int E)
{
    __shared__ int wsum[4];
    int tid = threadIdx.x, lane = tid & 63, wid = tid >> 6;
    int base = blockIdx.x*1024 + tid*4;
    int4 v = make_int4(0,0,0,0);
    if (base + 3 < N) v = *(const int4*)(cnt + base);
    else {
        if (base+0 < N) v.x = cnt[base+0];
        if (base+1 < N) v.y = cnt[base+1];
        if (base+2 < N) v.z = cnt[base+2];
    }
    int t0 = v.x, t1 = t0 + v.y, t2 = t1 + v.z, t3 = t2 + v.w;
    int inc = t3;
    #pragma unroll
    for (int o = 1; o < 64; o <<= 1){
        int u = __shfl_up(inc, o);
        if (lane >= o) inc += u;
    }
    if (lane == 63) wsum[wid] = inc;
    __syncthreads();
    int woff = 0;
    if (wid > 0) woff += wsum[0];
    if (wid > 1) woff += wsum[1];
    if (wid > 2) woff += wsum[2];
    int off = bsum[blockIdx.x] + woff + inc - t3;
    if (base+0 < N) rp[base+0] = off;
    if (base+1 < N) rp[base+1] = off + t0;
    if (base+2 < N) rp[base+2] = off + t1;
    if (base+3 < N) rp[base+3] = off + t2;
    if (blockIdx.x == 0 && tid == 0) rp[N] = E;
}

__global__ __launch_bounds__(256) void k_fill2(
    const int* __restrict__ preS, const int* __restrict__ preD,
    const int* __restrict__ postS, const int* __restrict__ postD, int E,
    const int* __restrict__ rpPre, const int* __restrict__ rankPre, int* __restrict__ csrPre,
    const int* __restrict__ rpPost, const int* __restrict__ rankPost, int* __restrict__ csrPost)
{
    int i = blockIdx.x*256 + threadIdx.x;
    int stride = gridDim.x*256;
    for (; i < E; i += stride){
        csrPre[rpPre[preD[i]] + rankPre[i]] = preS[i];
        csrPost[rpPost[postD[i]] + rankPost[i]] = postS[i];
    }
}

// ---------------- dual-side score GEMV: y[r] = h[r].wv + c0, fused max -------
// blocks [0, half): place side; [half, 2*half): trans side.
__global__ __launch_bounds__(256) void k_gemv2(
    const ushort_t* __restrict__ Ap, int P,
    const ushort_t* __restrict__ At, int T,
    const float* __restrict__ wvA, const float* __restrict__ wvB,
    const float* __restrict__ c0v, int c0iA, int c0iB,
    float* __restrict__ yA, float* __restrict__ yB,
    unsigned* __restrict__ MkA, unsigned* __restrict__ MkB)
{
    __shared__ float wm[4];
    int half = gridDim.x >> 1;
    int side = (blockIdx.x >= half);
    const ushort_t* A = side ? At : Ap;
    int M = side ? T : P;
    const float* wv = side ? wvB : wvA;
    float c0 = c0v[side ? c0iB : c0iA];
    float* y = side ? yB : yA;
    unsigned* Mk = side ? MkB : MkA;
    int b = side ? (blockIdx.x - half) : blockIdx.x;

    int tid = threadIdx.x, lane = tid & 63, wid = tid >> 6;
    int g = tid >> 4, gl = tid & 15;
    float w8[8];
    #pragma unroll
    for (int i = 0; i < 8; i++) w8[i] = wv[gl*8 + i];
    int stride = half*16;
    float lmax = -3.402823466e38f;
    for (int r = b*16 + g; r < M; r += stride){
        short8 u = *(const short8*)(A + (size_t)r*H + gl*8);
        float s = 0.f;
        #pragma unroll
        for (int i = 0; i < 8; i++) s += bf2f((ushort_t)u[i]) * w8[i];
        s += __shfl_xor(s, 1); s += __shfl_xor(s, 2);
        s += __shfl_xor(s, 4); s += __shfl_xor(s, 8);
        s += c0;
        if (gl == 0) y[r] = s;
        lmax = fmaxf(lmax, s);
    }
    #pragma unroll
    for (int o = 1; o < 64; o <<= 1) lmax = fmaxf(lmax, __shfl_xor(lmax, o));
    if (lane == 0) wm[wid] = lmax;
    __syncthreads();
    if (tid == 0){
        float m = fmaxf(fmaxf(wm[0], wm[1]), fmaxf(wm[2], wm[3]));
        atomicMax(Mk, fkey(m));
    }
}

// ---------------- edge weights in CSR order + softmax denominators -----------
// ew[j] = exp(y[csr[j]] - M); Sp += sum(ew). Replaces k_sumexp AND the
// 16x-redundant per-lane expf in the gather.
__global__ __launch_bounds__(256) void k_ew2(
    const int* __restrict__ csrPre, const int* __restrict__ csrPost, int E,
    const float* __restrict__ yA, const float* __restrict__ yB,
    const unsigned* __restrict__ MkA, const unsigned* __restrict__ MkB,
    float* __restrict__ ewA, float* __restrict__ ewB,
    float* __restrict__ SpA, float* __restrict__ SpB)
{
    __shared__ float red[4];
    int half = gridDim.x >> 1;
    int side = (blockIdx.x >= half);
    const int* csr = side ? csrPost : csrPre;
    const float* y = side ? yB : yA;
    float Mv = funkey((side ? MkB : MkA)[0]);
    float* ew = side ? ewB : ewA;
    float* Sp = side ? SpB : SpA;
    int b = side ? (blockIdx.x - half) : blockIdx.x;

    int tid = threadIdx.x, lane = tid & 63, wid = tid >> 6;
    int gid = b*256 + tid, stride = half*256;
    float ls = 0.f;
    for (int j = gid; j < E; j += stride){
        float w = expf(y[csr[j]] - Mv);
        ew[j] = w;
        ls += w;
    }
    #pragma unroll
    for (int o = 1; o < 64; o <<= 1) ls += __shfl_xor(ls, o);
    if (lane == 0) red[wid] = ls;
    __syncthreads();
    if (tid == 0) atomicAdd(Sp, red[0] + red[1] + red[2] + red[3]);
}

// ---------------- dual-side CSR gather of fp8 rows + sdeg --------------------
// side 0 (blocks < nbT): gather XP rows via csrPre/ewA -> GbA/sdegA (T rows)
// side 1: gather XT rows via csrPost/ewB -> GbB/sdegB (P rows)
__global__ __launch_bounds__(256) void k_gather2(
    const int* __restrict__ rpPre, const int* __restrict__ csrPre, int T,
    const int* __restrict__ rpPost, const int* __restrict__ csrPost, int P,
    const float* __restrict__ ewA, const float* __restrict__ ewB,
    const uchar_t* __restrict__ XP, const uchar_t* __restrict__ XT,
    ushort_t* __restrict__ GbA, ushort_t* __restrict__ GbB,
    float* __restrict__ sdegA, float* __restrict__ sdegB)
{
    int nbT = (T + 15) >> 4;
    int side = (blockIdx.x >= nbT);
    const int* rp   = side ? rpPost : rpPre;
    const int* csr  = side ? csrPost : csrPre;
    const float* ew = side ? ewB : ewA;
    const uchar_t* X = side ? XT : XP;
    ushort_t* G     = side ? GbB : GbA;
    float* sdeg     = side ? sdegB : sdegA;
    int Nrow        = side ? P : T;
    int b = side ? (blockIdx.x - nbT) : blockIdx.x;

    int tid = threadIdx.x;
    int g = tid >> 4, gl = tid & 15;          // 16 groups x 16 lanes
    int r = b*16 + g;
    if (r >= Nrow) return;
    int j0 = rp[r], j1 = rp[r+1];
    const int2* X8 = (const int2*)X;          // fp8 row = 16 int2 (128 fp8)
    float a[8] = {0.f,0.f,0.f,0.f,0.f,0.f,0.f,0.f};
    float se = 0.f;
    int j = j0;
    for (; j + 1 < j1; j += 2){
        int s0 = csr[j], s1 = csr[j+1];
        float e0 = ew[j], e1 = ew[j+1];
        int2 u0 = X8[(size_t)s0*16 + gl];
        int2 u1 = X8[(size_t)s1*16 + gl];
        se += e0 + e1;
        acc8f8(a, u0, e0);
        acc8f8(a, u1, e1);
    }
    if (j < j1){
        int s0 = csr[j];
        float e0 = ew[j];
        int2 u0 = X8[(size_t)s0*16 + gl];
        se += e0;
        acc8f8(a, u0, e0);
    }
    int4 o;
    o.x = (int)((((unsigned)f2bf(a[1])) << 16) | (unsigned)f2bf(a[0]));
    o.y = (int)((((unsigned)f2bf(a[3])) << 16) | (unsigned)f2bf(a[2]));
    o.z = (int)((((unsigned)f2bf(a[5])) << 16) | (unsigned)f2bf(a[4]));
    o.w = (int)((((unsigned)f2bf(a[7])) << 16) | (unsigned)f2bf(a[6]));
    ((int4*)G)[(size_t)r*16 + gl] = o;
    if (gl == 0) sdeg[r] = se;
}

// ---------------- dual-side update GEMM --------------------------------------
// out = relu(A1 + A1@Wtop + invS*(G@Wc + sdeg*bc) + b)   [IN-PLACE: out == A1]
// blocks [0, gridT): transition update; [gridT, gridT+gridP): place update.
// 3-buffer LDS ring (2-deep prefetch, counted vmcnt, raw s_barrier), XOR-
// swizzled via pre-swizzled global source. Residual A1 via identity-MFMA.
// STORE=false (last layer): no out/fp8 stores, only colsum; vmcnt re-derived.
template<bool STORE>
__global__ __launch_bounds__(256, 4) void k_up2(
    ushort_t* trans_h, ushort_t* place_h,
    const ushort_t* __restrict__ GbA, const ushort_t* __restrict__ GbB,
    const ushort_t* __restrict__ WTl,
    const float* __restrict__ tub, const float* __restrict__ pub,
    const float* __restrict__ bcA, const float* __restrict__ bcB,
    const float* __restrict__ sc4,          // [MkA,SpA,MkB,SpB]
    const float* __restrict__ sdegA, const float* __restrict__ sdegB,
    uchar_t* __restrict__ XT, uchar_t* __restrict__ XP,
    int T, int P, int gridT, int gridP,
    float* __restrict__ meanT, float* __restrict__ meanP)
{
    __shared__ __align__(16) char As[3*8192];   // 3 x (A1 4KB | A2 4KB)
    __shared__ float csum[H];
    int side = (blockIdx.x >= gridT);
    ushort_t* A1        = side ? place_h : trans_h;
    const ushort_t* A2  = side ? GbB : GbA;
    const ushort_t* WT  = WTl + (side ? 32768 : 0);
    const float* bias   = side ? pub : tub;
    const float* bcp    = side ? bcB : bcA;
    const float* sdeg   = side ? sdegB : sdegA;
    uchar_t* outF8      = side ? XP : XT;
    int M               = side ? P : T;
    int G               = side ? gridP : gridT;
    int t0              = side ? (blockIdx.x - gridT) : blockIdx.x;
    float* colsum       = side ? meanP : meanT;
    float invS = 1.f / (side ? sc4[3] : sc4[1]);

    int tid = threadIdx.x;
    int lane = tid & 63, wid = tid >> 6;
    int quad = lane >> 4, l15 = lane & 15;
    int strip = wid*32;
    short8 bfr1[2][4], bfr2[2][4];
    float bcol[2], bc2[2];
    #pragma unroll
    for (int j = 0; j < 2; j++){
        int col = strip + j*16 + l15;
        #pragma unroll
        for (int kk = 0; kk < 4; kk++){
            bfr1[j][kk] = *(const short8*)(WT + (size_t)col*256 + kk*32 + quad*8);
            bfr2[j][kk] = *(const short8*)(WT + (size_t)col*256 + 128 + kk*32 + quad*8);
        }
        bcol[j] = bias[col];
        bc2[j]  = bcp[col];
    }
    // identity B-fragments: transpose the wave's A1 fragment window into C-layout
    short8 If0, If1;
    #pragma unroll
    for (int e = 0; e < 8; e++){
        int kloc = quad*8 + e;
        If0[e] = (kloc == l15)      ? (short)0x3F80 : (short)0;
        If1[e] = (kloc == l15 + 16) ? (short)0x3F80 : (short)0;
    }
    if constexpr (!STORE){ if (tid < H) csum[tid] = 0.f; }
    float cs[2] = {0.f, 0.f};

    int tiles = (M + 15) >> 4;
    if (t0 >= tiles) return;
    int srow = tid >> 4;
    int su = (tid & 15) ^ srow;
    const ushort_t* g1b = A1 + (size_t)srow*H + su*8;
    const ushort_t* g2b = A2 + (size_t)srow*H + su*8;
    char* AsB = As;

    #define STAGE_UP(bo, t) do { \
        gll16(g1b + (size_t)(t)*(16*H), AsB + (bo) + (wid<<10)); \
        gll16(g2b + (size_t)(t)*(16*H), AsB + (bo) + 4096 + (wid<<10)); \
    } while(0)

    STAGE_UP(0, t0);
    int t1p = t0 + G;
    if (t1p < tiles){
        STAGE_UP(8192, t1p);
        asm volatile("s_waitcnt vmcnt(2)\ns_barrier" ::: "memory");
    } else {
        asm volatile("s_waitcnt vmcnt(0)\ns_barrier" ::: "memory");
    }

    int t = t0, bo = 0;
    for (;;){
        const char* rb = AsB + bo;
        int row0 = t << 4;
        float4 sd4 = *(const float4*)(sdeg + row0 + quad*4);
        float sdv[4] = {sd4.x, sd4.y, sd4.z, sd4.w};
        short8 a1f[4], a2f[4];
        #pragma unroll
        for (int kk = 0; kk < 4; kk++){
            int sw = ((((kk<<2)+quad) ^ l15) << 4);
            a1f[kk] = *(const short8*)(rb + (l15<<8) + sw);
            a2f[kk] = *(const short8*)(rb + 4096 + (l15<<8) + sw);
        }
        short8 ares = *(const short8*)(rb + (l15<<8) + ((((wid<<2)+quad) ^ l15) << 4));
        floatx4 acc1[2], acc2[2];
        acc1[0] = __builtin_amdgcn_mfma_f32_16x16x32_bf16(ares, If0, (floatx4)0.f, 0,0,0);
        acc1[1] = __builtin_amdgcn_mfma_f32_16x16x32_bf16(ares, If1, (floatx4)0.f, 0,0,0);
        acc2[0] = (floatx4)0.f; acc2[1] = (floatx4)0.f;
        #pragma unroll
        for (int j = 0; j < 2; j++){
            #pragma unroll
            for (int kk = 0; kk < 4; kk++)
                acc1[j] = __builtin_amdgcn_mfma_f32_16x16x32_bf16(a1f[kk], bfr1[j][kk], acc1[j], 0,0,0);
            #pragma unroll
            for (int kk = 0; kk < 4; kk++)
                acc2[j] = __builtin_amdgcn_mfma_f32_16x16x32_bf16(a2f[kk], bfr2[j][kk], acc2[j], 0,0,0);
        }
        #pragma unroll
        for (int j = 0; j < 2; j++){
            int col = strip + j*16 + l15;
            #pragma unroll
            for (int rr = 0; rr < 4; rr++){
                int grow = row0 + quad*4 + rr;
                float v = acc1[j][rr] + invS*(acc2[j][rr] + sdv[rr]*bc2[j]) + bcol[j];
                v = fmaxf(v, 0.f);
                if constexpr (STORE){
                    A1[(size_t)grow*H + col] = f2bf(v);       // 8 ushort stores
                    outF8[(size_t)grow*H + col] = f2fp8(v);   // 8 byte stores
                } else {
                    cs[j] += v;
                }
            }
        }
        int tn = t + G;
        if (tn >= tiles) break;
        int tnn = tn + G;
        int bo2 = bo + 8192; if (bo2 >= 24576) bo2 = 0;
        int bo3 = bo2 + 8192; if (bo3 >= 24576) bo3 = 0;
        // wait for stage(tn): ops newer = 1 sdeg + (16|0) stores (+2 stage)
        if (tnn < tiles){
            STAGE_UP(bo3, tnn);
            if constexpr (STORE) asm volatile("s_waitcnt vmcnt(19)\ns_barrier" ::: "memory");
            else                 asm volatile("s_waitcnt vmcnt(3)\ns_barrier" ::: "memory");
        } else {
            if constexpr (STORE) asm volatile("s_waitcnt vmcnt(17)\ns_barrier" ::: "memory");
            else                 asm volatile("s_waitcnt vmcnt(1)\ns_barrier" ::: "memory");
        }
        t = tn; bo = bo2;
    }
    #undef STAGE_UP
    if constexpr (!STORE){
        #pragma unroll
        for (int j = 0; j < 2; j++){
            float v = cs[j];
            v += __shfl_xor(v, 16); v += __shfl_xor(v, 32);
            if (quad == 0) atomicAdd(&csum[strip + j*16 + l15], v);
        }
        __syncthreads();
        if (tid < H) atomicAdd(&colsum[tid], csum[tid]);
    }
}

// ---------------- tiny MLP head ----------------
__global__ __launch_bounds__(256) void k_head(
    const float* __restrict__ meanP, const float* __restrict__ meanT,
    float invP, float invT,
    const float* __restrict__ Wpp, const float* __restrict__ bpp,
    const float* __restrict__ Wtp, const float* __restrict__ btp,
    const float* __restrict__ prefix,
    const float* __restrict__ W1, const float* __restrict__ b1,
    const float* __restrict__ W2, const float* __restrict__ b2,
    float* __restrict__ h2g)
{
    __shared__ float comb[384];
    __shared__ float h1s[256];
    int tid = threadIdx.x;
    if (tid < 128){
        float a = bpp[tid];
        for (int k = 0; k < 128; k++) a += meanP[k]*invP*Wpp[k*H + tid];
        comb[tid] = a;
        comb[256 + tid] = prefix[tid];
    } else {
        int c = tid - 128;
        float a = btp[c];
        for (int k = 0; k < 128; k++) a += meanT[k]*invT*Wtp[k*H + c];
        comb[128 + c] = a;
    }
    __syncthreads();
    {
        float a = b1[tid];
        for (int k = 0; k < 384; k++) a += comb[k]*W1[k*256 + tid];
        h1s[tid] = fmaxf(a, 0.f);
    }
    __syncthreads();
    if (tid < 128){
        float a = b2[tid];
        for (int k = 0; k < 256; k++) a += h1s[k]*W2[k*H + tid];
        h2g[tid] = fmaxf(a, 0.f);
    }
}

// ---------------- logits + sigmoid ----------------
__global__ __launch_bounds__(256) void k_logits(
    const float* __restrict__ h2g, const float* __restrict__ W3,
    const float* __restrict__ b3, float* __restrict__ out, int T)
{
    __shared__ float h2l[128];
    int tid = threadIdx.x;
    if (tid < 128) h2l[tid] = h2g[tid];
    __syncthreads();
    int t = blockIdx.x*256 + tid;
    if (t >= T) return;
    float a = b3[t];
    #pragma unroll 8
    for (int k = 0; k < 128; k++) a += h2l[k]*W3[(size_t)k*T + t];
    out[t] = 1.f/(1.f + expf(-a));
}

// ---------------- launch ----------------
extern "C" void kernel_launch(void* const* d_in, const int* in_sizes, int n_in,
                              void* d_out, int out_size, void* d_ws, size_t ws_size,
                              hipStream_t stream)
{
    (void)n_in; (void)out_size; (void)ws_size;
    const float* pf    = (const float*)d_in[0];
    const float* tf    = (const float*)d_in[1];
    const float* pe    = (const float*)d_in[2];
    const int*   pre   = (const int*)d_in[3];
    const int*   post  = (const int*)d_in[4];
    const float* W_pe  = (const float*)d_in[5];
    const float* b_pe  = (const float*)d_in[6];
    const float* W_te  = (const float*)d_in[7];
    const float* b_te  = (const float*)d_in[8];
    const float* W_pr  = (const float*)d_in[9];
    const float* b_pr  = (const float*)d_in[10];
    const float* p2t_W = (const float*)d_in[11];
    const float* p2t_b = (const float*)d_in[12];
    const float* t2p_W = (const float*)d_in[13];
    const float* t2p_b = (const float*)d_in[14];
    const float* pu_W  = (const float*)d_in[15];
    const float* pu_b  = (const float*)d_in[16];
    const float* tu_W  = (const float*)d_in[17];
    const float* tu_b  = (const float*)d_in[18];
    const float* pa_W  = (const float*)d_in[19];
    const float* pa_b  = (const float*)d_in[20];
    const float* ta_W  = (const float*)d_in[21];
    const float* ta_b  = (const float*)d_in[22];
    const float* W_pp  = (const float*)d_in[23];
    const float* b_pp  = (const float*)d_in[24];
    const float* W_tp  = (const float*)d_in[25];
    const float* b_tp  = (const float*)d_in[26];
    const float* W1    = (const float*)d_in[27];
    const float* b1    = (const float*)d_in[28];
    const float* W2    = (const float*)d_in[29];
    const float* b2    = (const float*)d_in[30];
    const float* W3    = (const float*)d_in[31];
    const float* b3    = (const float*)d_in[32];

    int P = in_sizes[0];
    int T = in_sizes[1] / 8;
    int E = in_sizes[3] / 2;
    int plen = in_sizes[2];
    int L = in_sizes[11] / (H*H);

    float* ws = (float*)d_ws;
    size_t fP = (size_t)P*H, fT = (size_t)T*H;
    size_t fN = (fP > fT) ? fP : fT;
    int   Nmax = (P > T) ? P : T;

    float* yA    = ws;                    // [Nmax] place-side scores
    float* yB    = yA + Nmax;             // [Nmax] trans-side scores
    float* sdegA = yB + Nmax;             // [Nmax] per-trans sum of exp
    float* sdegB = sdegA + Nmax;          // [Nmax] per-place sum of exp
    float* sc    = sdegB + Nmax;          // 16 softmax slots
    float* meanP   = sc + 16;
    float* meanT   = sc + 144;
    float* prefix  = sc + 272;
    float* h2g     = sc + 400;            // end at sc+544
    float* wvv  = sc + 544;               // [L*2*128] folded score vectors
    float* c0v  = wvv + (size_t)L*256;    // [32] folded score consts (padded)
    float* bcv  = c0v + 32;               // [L*2*128] folded bias rows

    ushort_t* bh = (ushort_t*)(bcv + (size_t)L*256);
    ushort_t* place_h = bh;               // [P,128] bf16 (updated IN-PLACE)
    ushort_t* trans_h = place_h + fP;     // [T,128] bf16 (updated IN-PLACE)
    ushort_t* GbA     = trans_h + fT;     // [Nmax,128] gathered places (per trans)
    ushort_t* GbB     = GbA + fN;         // [Nmax,128] gathered transes (per place)
    ushort_t* WTb     = GbB + fN;         // L*65536 bf16 combined update weights
    uchar_t*  XP      = (uchar_t*)(WTb + (size_t)L*65536);  // [P,128] fp8 shadow
    uchar_t*  XT      = XP + fP;                             // [T,128] fp8 shadow

    int* iw = (int*)(XT + fT);
    int* cntPre  = iw;                 // [T]
    int* cntPost = cntPre + T;         // [P]
    int* rpPre   = cntPost + P;        // [T+1]
    int* rpPost  = rpPre + (T + 1);    // [P+1]
    int* csrPre  = rpPost + (P + 2);   // [E]
    int* csrPost = csrPre + E;         // [E]
    int* rankPre = csrPost + E;        // [E]
    int* rankPost= rankPre + E;        // [E]
    int* bsumA   = rankPost + E;       // [256]
    int* bsumB   = bsumA + 256;        // [256]

    // edge-weight buffers ALIAS the rank arrays (dead after k_fill2) — keeps
    // total workspace footprint at the R4-validated level.
    float* ewA = (float*)rankPre;      // [E] edge weights, csrPre order
    float* ewB = (float*)rankPost;     // [E] edge weights, csrPost order

    const int* pre_src  = pre;          const int* pre_dst  = pre + E;
    const int* post_src = post;         const int* post_dst = post + E;

    int wtot = L*32768;
    int nbT = (T + 1023)/1024, nbP = (P + 1023)/1024;

    // update-GEMM grids: ring, 5 tiles/block, both sides fused in one launch
    int tilesP = (P + 15) >> 4, tilesT = (T + 15) >> 4;
    int gridP = (tilesP + 4)/5, gridT = (tilesT + 4)/5;
    int nbTg = (T + 15) >> 4, nbPg = (P + 15) >> 4;

    k_init_small<<<1, 128, 0, stream>>>(pe, plen, W_pr, b_pr, prefix, meanP, meanT, sc);
    k_wconv<<<(wtot + 255)/256, 256, 0, stream>>>(tu_W, pu_W, WTb, wtot);
    k_wfold<<<(wtot + 255)/256, 256, 0, stream>>>(p2t_W, t2p_W, tu_W, pu_W, WTb, wtot);
    k_wsmall<<<L*2, 128, 0, stream>>>(p2t_W, t2p_W, tu_W, pu_W, p2t_b, t2p_b,
                                      ta_W, ta_b, pa_W, pa_b, wvv, c0v, bcv);
    k_zero_ints<<<256, 256, 0, stream>>>(iw, P + T);
    k_hist2<<<2048, 256, 0, stream>>>(pre_dst, post_dst, E,
                                      cntPre, cntPost, rankPre, rankPost);
    k_scan_part<<<nbT, 256, 0, stream>>>(cntPre, T, bsumA);
    k_scan_bsum<<<1, 256, 0, stream>>>(bsumA, nbT);
    k_scan_final<<<nbT, 256, 0, stream>>>(cntPre, T, bsumA, rpPre, E);
    k_scan_part<<<nbP, 256, 0, stream>>>(cntPost, P, bsumB);
    k_scan_bsum<<<1, 256, 0, stream>>>(bsumB, nbP);
    k_scan_final<<<nbP, 256, 0, stream>>>(cntPost, P, bsumB, rpPost, E);
    k_fill2<<<1024, 256, 0, stream>>>(pre_src, pre_dst, post_src, post_dst, E,
                                      rpPre, rankPre, csrPre,
                                      rpPost, rankPost, csrPost);

    k_embed_place<<<(P*32 + 255)/256, 256, 0, stream>>>(pf, W_pe, b_pe, place_h, XP, P);
    k_embed_trans<<<(T*32 + 255)/256, 256, 0, stream>>>(tf, W_te, b_te, trans_h, XT, T);

    for (int l = 0; l < L; l++){
        const ushort_t* WTl = WTb + (size_t)l*65536;
        const float* pub  = pu_b  + (size_t)l*H;
        const float* tub  = tu_b  + (size_t)l*H;
        const float* wvA  = wvv + (size_t)(l*2 + 0)*H;
        const float* wvB  = wvv + (size_t)(l*2 + 1)*H;
        const float* bcA  = bcv + (size_t)(l*2 + 0)*H;
        const float* bcB  = bcv + (size_t)(l*2 + 1)*H;
        unsigned* MkA = (unsigned*)(sc + l*4 + 0);   float* SpA = sc + l*4 + 1;
        unsigned* MkB = (unsigned*)(sc + l*4 + 2);   float* SpB = sc + l*4 + 3;
        int last = (l == L-1);

        // scores (both sides) -> edge weights + denominators -> gathers
        k_gemv2<<<1024, 256, 0, stream>>>(place_h, P, trans_h, T, wvA, wvB,
                                          c0v, l*2 + 0, l*2 + 1, yA, yB, MkA, MkB);
        k_ew2<<<1024, 256, 0, stream>>>(csrPre, csrPost, E, yA, yB, MkA, MkB,
                                        ewA, ewB, SpA, SpB);
        k_gather2<<<nbTg + nbPg, 256, 0, stream>>>(rpPre, csrPre, T,
                                                   rpPost, csrPost, P,
                                                   ewA, ewB, XP, XT,
                                                   GbA, GbB, sdegA, sdegB);
        // fused in-place updates (both sides)
        if (last)
            k_up2<false><<<gridT + gridP, 256, 0, stream>>>(
                trans_h, place_h, GbA, GbB, WTl, tub, pub, bcA, bcB,
                sc + l*4, sdegA, sdegB, XT, XP, T, P, gridT, gridP, meanT, meanP);
        else
            k_up2<true><<<gridT + gridP, 256, 0, stream>>>(
                trans_h, place_h, GbA, GbB, WTl, tub, pub, bcA, bcB,
                sc + l*4, sdegA, sdegB, XT, XP, T, P, gridT, gridP, meanT, meanP);
    }

    k_head<<<1, 256, 0, stream>>>(meanP, meanT, 1.f/(float)P, 1.f/(float)T,
                                  W_pp, b_pp, W_tp, b_tp, prefix, W1, b1, W2, b2, h2g);
    k_logits<<<(T + 255)/256, 256, 0, stream>>>(h2g, W3, b3, (float*)d_out, T);
}

// Round 7
// 657.449 us; speedup vs baseline: 1.3060x; 1.0408x over previous
//
#include <hip/hip_runtime.h>
#include <cstddef>

#define H 128

typedef unsigned short ushort_t;
typedef unsigned char uchar_t;
typedef __attribute__((ext_vector_type(8))) short short8;
typedef __attribute__((ext_vector_type(4))) float floatx4;
typedef __attribute__((ext_vector_type(2))) float floatx2;

// ---------------- helpers ----------------
__device__ __forceinline__ unsigned fkey(float f){
    unsigned u = __float_as_uint(f);
    return (u & 0x80000000u) ? ~u : (u | 0x80000000u);
}
__device__ __forceinline__ float funkey(unsigned k){
    unsigned u = (k & 0x80000000u) ? (k ^ 0x80000000u) : ~k;
    return __uint_as_float(u);
}
__device__ __forceinline__ ushort_t f2bf(float f){
    unsigned u = __float_as_uint(f);
    u += 0x7fffu + ((u >> 16) & 1u);      // round-to-nearest-even
    return (ushort_t)(u >> 16);
}
__device__ __forceinline__ float bf2f(ushort_t h){
    return __uint_as_float(((unsigned)h) << 16);
}
__device__ __forceinline__ uchar_t f2fp8(float v){
    int p = __builtin_amdgcn_cvt_pk_fp8_f32(v, v, 0, false);
    return (uchar_t)(p & 0xff);
}
// async global -> LDS, 16B per lane. LDS dest = wave-uniform base + lane*16.
__device__ __forceinline__ void gll16(const void* g, void* l){
    __builtin_amdgcn_global_load_lds(
        (const __attribute__((address_space(1))) unsigned int*)g,
        (__attribute__((address_space(3))) unsigned int*)l, 16, 0, 0);
}
// accumulate 8 fp8 (one int2) into 8 fp32 with weight
__device__ __forceinline__ void acc8f8(float* a, int2 u, float w){
    floatx2 p;
    p = __builtin_amdgcn_cvt_pk_f32_fp8(u.x, false); a[0] += w*p.x; a[1] += w*p.y;
    p = __builtin_amdgcn_cvt_pk_f32_fp8(u.x, true);  a[2] += w*p.x; a[3] += w*p.y;
    p = __builtin_amdgcn_cvt_pk_f32_fp8(u.y, false); a[4] += w*p.x; a[5] += w*p.y;
    p = __builtin_amdgcn_cvt_pk_f32_fp8(u.y, true);  a[6] += w*p.x; a[7] += w*p.y;
}

// ---------------- embeddings (write bf16 states + fp8 shadow) ----------------
__global__ __launch_bounds__(256) void k_embed_place(
    const float* __restrict__ pf, const float* __restrict__ Wpe,
    const float* __restrict__ bpe, ushort_t* __restrict__ out,
    uchar_t* __restrict__ outf8, int P)
{
    int idx = blockIdx.x*256 + threadIdx.x;     // 4-elem group index over P*32
    if (idx >= P*32) return;
    int p = idx >> 5, q = (idx & 31) << 2;
    float v = pf[p];
    float4 w = *(const float4*)(Wpe + q);
    float4 b = *(const float4*)(bpe + q);
    float v0 = v*w.x + b.x, v1 = v*w.y + b.y, v2 = v*w.z + b.z, v3 = v*w.w + b.w;
    ushort4 o;
    o.x = f2bf(v0); o.y = f2bf(v1); o.z = f2bf(v2); o.w = f2bf(v3);
    *(ushort4*)(out + (size_t)p*H + q) = o;
    int pk = __builtin_amdgcn_cvt_pk_fp8_f32(v0, v1, 0, false);
    pk = __builtin_amdgcn_cvt_pk_fp8_f32(v2, v3, pk, true);
    *(int*)(outf8 + (size_t)p*H + q) = pk;
}

__global__ __launch_bounds__(256) void k_embed_trans(
    const float* __restrict__ tf, const float* __restrict__ Wte,
    const float* __restrict__ bte, ushort_t* __restrict__ out,
    uchar_t* __restrict__ outf8, int T)
{
    __shared__ float Wl[8*H];
    __shared__ float Bl[H];
    int tid = threadIdx.x;
    #pragma unroll
    for (int t = 0; t < 4; t++) Wl[tid + t*256] = Wte[tid + t*256];
    if (tid < H) Bl[tid] = bte[tid];
    __syncthreads();
    int idx = blockIdx.x*256 + tid;
    if (idx >= T*32) return;
    int t = idx >> 5, q = (idx & 31) << 2;
    float4 acc = *(float4*)(&Bl[q]);
    #pragma unroll
    for (int k = 0; k < 8; k++){
        float s = tf[(size_t)t*8 + k];
        float4 w = *(float4*)(&Wl[k*H + q]);
        acc.x += s*w.x; acc.y += s*w.y; acc.z += s*w.z; acc.w += s*w.w;
    }
    ushort4 o;
    o.x = f2bf(acc.x); o.y = f2bf(acc.y); o.z = f2bf(acc.z); o.w = f2bf(acc.w);
    *(ushort4*)(out + (size_t)t*H + q) = o;
    int pk = __builtin_amdgcn_cvt_pk_fp8_f32(acc.x, acc.y, 0, false);
    pk = __builtin_amdgcn_cvt_pk_fp8_f32(acc.z, acc.w, pk, true);
    *(int*)(outf8 + (size_t)t*H + q) = pk;
}

// prefix embedding + zero mean shadow copies + softmax slots
__global__ void k_init_small(const float* __restrict__ pe, int plen,
                             const float* __restrict__ Wpr, const float* __restrict__ bpr,
                             float* __restrict__ prefix, float* __restrict__ meanPsh,
                             float* __restrict__ meanTsh, float* __restrict__ slots)
{
    int c = threadIdx.x;  // 128 threads
    float a = bpr[c];
    for (int k = 0; k < plen; k++) a += pe[k]*Wpr[k*H + c];
    prefix[c] = a;
    for (int i = c; i < 4096; i += 128){ meanPsh[i] = 0.f; meanTsh[i] = 0.f; }
    if (c < 16) slots[c] = 0.f;   // fkey-space 0 == -inf; Sp slots start at 0
}

// ---------------- combined weight prep: A1-half + folded Wc ------------------
// WT per layer: [side0: tu-combined 128x256][side1: pu-combined 128x256]
// k 0..127 = Wtop (bf16 of Bm upper half, transposed); k 128..255 = Wc fold.
__global__ __launch_bounds__(256) void k_wprep2(
    const float* __restrict__ p2t_W, const float* __restrict__ t2p_W,
    const float* __restrict__ tu_W,  const float* __restrict__ pu_W,
    ushort_t* __restrict__ WT, int total)   // total = L*32768
{
    int e = blockIdx.x*256 + threadIdx.x;
    if (e >= total) return;
    int l = e / 32768, oo = e - l*32768;
    int side = oo >> 14, o2 = oo & 16383;
    int n = o2 >> 7, k = o2 & 127;
    const float* A  = side ? (t2p_W + (size_t)l*16384) : (p2t_W + (size_t)l*16384);
    const float* Bm = side ? (pu_W  + (size_t)l*32768) : (tu_W  + (size_t)l*32768);
    ushort_t* dst = WT + (size_t)l*65536 + (size_t)side*32768 + n*256;
    dst[k] = f2bf(Bm[(size_t)k*H + n]);                  // Wtop half
    const float* Ar = A + (size_t)k*H;
    const float* Bc = Bm + (size_t)128*H + n;
    float s = 0.f;
    #pragma unroll 4
    for (int j = 0; j < 128; j++) s += Ar[j] * Bc[(size_t)j*H];
    dst[128 + k] = f2bf(s);                              // folded Wc half
}

// ---------------- folded small vectors: wv, bc, c0 ---------------------------
__global__ __launch_bounds__(128) void k_wsmall(
    const float* __restrict__ p2t_W, const float* __restrict__ t2p_W,
    const float* __restrict__ tu_W,  const float* __restrict__ pu_W,
    const float* __restrict__ p2t_b, const float* __restrict__ t2p_b,
    const float* __restrict__ ta_W,  const float* __restrict__ ta_b,
    const float* __restrict__ pa_W,  const float* __restrict__ pa_b,
    float* __restrict__ wv, float* __restrict__ c0v, float* __restrict__ bcv)
{
    int b = blockIdx.x, l = b >> 1, side = b & 1;
    const float* A  = side ? (t2p_W + (size_t)l*16384) : (p2t_W + (size_t)l*16384);
    const float* Bm = side ? (pu_W  + (size_t)l*32768) : (tu_W  + (size_t)l*32768);
    const float* ab = side ? (t2p_b + (size_t)l*H) : (p2t_b + (size_t)l*H);
    const float* av = side ? (pa_W  + (size_t)l*H) : (ta_W  + (size_t)l*H);
    float asc       = side ? pa_b[l] : ta_b[l];
    int tid = threadIdx.x;
    int o = (l*2 + side)*H;
    float s = 0.f;
    for (int n = 0; n < 128; n++) s += A[(size_t)tid*H + n] * av[n];
    wv[o + tid] = s;
    float s2 = 0.f;
    for (int j = 0; j < 128; j++) s2 += ab[j] * Bm[(size_t)(128+j)*H + tid];
    bcv[o + tid] = s2;
    if (tid == 0){
        float c = 0.f;
        for (int n = 0; n < 128; n++) c += ab[n]*av[n];
        c0v[l*2 + side] = c + asc;
    }
}

// ---------------- CSR build ----------------
__global__ __launch_bounds__(256) void k_zero_ints(int* __restrict__ p, int n)
{
    int i = blockIdx.x*256 + threadIdx.x;
    int stride = gridDim.x*256;
    for (; i < n; i += stride) p[i] = 0;
}

__global__ __launch_bounds__(256) void k_hist2(
    const int* __restrict__ preD, const int* __restrict__ postD, int E,
    int* __restrict__ cntPre, int* __restrict__ cntPost,
    int* __restrict__ rankPre, int* __restrict__ rankPost)
{
    int i = blockIdx.x*256 + threadIdx.x;
    int stride = gridDim.x*256;
    for (; i < E; i += stride){
        rankPre[i] = atomicAdd(&cntPre[preD[i]], 1);
        rankPost[i] = atomicAdd(&cntPost[postD[i]], 1);
    }
}

__global__ __launch_bounds__(256) void k_scan_part(
    const int* __restrict__ cnt, int N, int* __restrict__ bsum)
{
    __shared__ int wsum[4];
    int tid = threadIdx.x, lane = tid & 63, wid = tid >> 6;
    int base = blockIdx.x*1024 + tid*4;
    int4 v = make_int4(0,0,0,0);
    if (base + 3 < N) v = *(const int4*)(cnt + base);
    else {
        if (base+0 < N) v.x = cnt[base+0];
        if (base+1 < N) v.y = cnt[base+1];
        if (base+2 < N) v.z = cnt[base+2];
    }
    int s = v.x + v.y + v.z + v.w;
    #pragma unroll
    for (int o = 1; o < 64; o <<= 1) s += __shfl_xor(s, o);
    if (lane == 0) wsum[wid] = s;
    __syncthreads();
    if (tid == 0) bsum[blockIdx.x] = wsum[0] + wsum[1] + wsum[2] + wsum[3];
}

__global__ __launch_bounds__(256) void k_scan_bsum(int* __restrict__ bsum, int nb)
{
    __shared__ int wsum[4];
    int tid = threadIdx.x, lane = tid & 63, wid = tid >> 6;
    int x = (tid < nb) ? bsum[tid] : 0;
    int inc = x;
    #pragma unroll
    for (int o = 1; o < 64; o <<= 1){
        int u = __shfl_up(inc, o);
        if (lane >= o) inc += u;
    }
    if (lane == 63) wsum[wid] = inc;
    __syncthreads();
    int woff = 0;
    if (wid > 0) woff += wsum[0];
    if (wid > 1) woff += wsum[1];
    if (wid > 2) woff += wsum[2];
    if (tid < nb) bsum[tid] = woff + inc - x;
}

__global__ __launch_bounds__(256) void k_scan_final(
    const int* __restrict__ cnt, int N, const int* __restrict__ bsum,
    int* __restrict__ rp, int E)
{
    __shared__ int wsum[4];
    int tid = threadIdx.x, lane = tid & 63, wid = tid >> 6;
    int base = blockIdx.x*1024 + tid*4;
    int4 v = make_int4(0,0,0,0);
    if (base + 3 < N) v = *(const int4*)(cnt + base);
    else {
        if (base+0 < N) v.x = cnt[base+0];
        if (base+1 < N) v.y = cnt[base+1];
        if (base+2 < N) v.z = cnt[base+2];
    }
    int t0 = v.x, t1 = t0 + v.y, t2 = t1 + v.z, t3 = t2 + v.w;
    int inc = t3;
    #pragma unroll
    for (int o = 1; o < 64; o <<= 1){
        int u = __shfl_up(inc, o);
        if (lane >= o) inc += u;
    }
    if (lane == 63) wsum[wid] = inc;
    __syncthreads();
    int woff = 0;
    if (wid > 0) woff += wsum[0];
    if (wid > 1) woff += wsum[1];
    if (wid > 2) woff += wsum[2];
    int off = bsum[blockIdx.x] + woff + inc - t3;
    if (base+0 < N) rp[base+0] = off;
    if (base+1 < N) rp[base+1] = off + t0;
    if (base+2 < N) rp[base+2] = off + t1;
    if (base+3 < N) rp[base+3] = off + t2;
    if (blockIdx.x == 0 && tid == 0) rp[N] = E;
}

__global__ __launch_bounds__(256) void k_fill2(
    const int* __restrict__ preS, const int* __restrict__ preD,
    const int* __restrict__ postS, const int* __restrict__ postD, int E,
    const int* __restrict__ rpPre, const int* __restrict__ rankPre, int* __restrict__ csrPre,
    const int* __restrict__ rpPost, const int* __restrict__ rankPost, int* __restrict__ csrPost)
{
    int i = blockIdx.x*256 + threadIdx.x;
    int stride = gridDim.x*256;
    for (; i < E; i += stride){
        csrPre[rpPre[preD[i]] + rankPre[i]] = preS[i];
        csrPost[rpPost[postD[i]] + rankPost[i]] = postS[i];
    }
}

// ---------------- dual-side score GEMV: y[r] = h[r].wv + c0, fused max -------
__global__ __launch_bounds__(256) void k_gemv2(
    const ushort_t* __restrict__ Ap, int P,
    const ushort_t* __restrict__ At, int T,
    const float* __restrict__ wvA, const float* __restrict__ wvB,
    const float* __restrict__ c0v, int c0iA, int c0iB,
    float* __restrict__ yA, float* __restrict__ yB,
    unsigned* __restrict__ MkA, unsigned* __restrict__ MkB)
{
    __shared__ float wm[4];
    int half = gridDim.x >> 1;
    int side = (blockIdx.x >= half);
    const ushort_t* A = side ? At : Ap;
    int M = side ? T : P;
    const float* wv = side ? wvB : wvA;
    float c0 = c0v[side ? c0iB : c0iA];
    float* y = side ? yB : yA;
    unsigned* Mk = side ? MkB : MkA;
    int b = side ? (blockIdx.x - half) : blockIdx.x;

    int tid = threadIdx.x, lane = tid & 63, wid = tid >> 6;
    int g = tid >> 4, gl = tid & 15;
    float w8[8];
    #pragma unroll
    for (int i = 0; i < 8; i++) w8[i] = wv[gl*8 + i];
    int stride = half*16;
    float lmax = -3.402823466e38f;
    for (int r = b*16 + g; r < M; r += stride){
        short8 u = *(const short8*)(A + (size_t)r*H + gl*8);
        float s = 0.f;
        #pragma unroll
        for (int i = 0; i < 8; i++) s += bf2f((ushort_t)u[i]) * w8[i];
        s += __shfl_xor(s, 1); s += __shfl_xor(s, 2);
        s += __shfl_xor(s, 4); s += __shfl_xor(s, 8);
        s += c0;
        if (gl == 0) y[r] = s;
        lmax = fmaxf(lmax, s);
    }
    #pragma unroll
    for (int o = 1; o < 64; o <<= 1) lmax = fmaxf(lmax, __shfl_xor(lmax, o));
    if (lane == 0) wm[wid] = lmax;
    __syncthreads();
    if (tid == 0){
        float m = fmaxf(fmaxf(wm[0], wm[1]), fmaxf(wm[2], wm[3]));
        atomicMax(Mk, fkey(m));
    }
}

// ---------------- edge weights in CSR order + softmax denominators -----------
__global__ __launch_bounds__(256) void k_ew2(
    const int* __restrict__ csrPre, const int* __restrict__ csrPost, int E,
    const float* __restrict__ yA, const float* __restrict__ yB,
    const unsigned* __restrict__ MkA, const unsigned* __restrict__ MkB,
    float* __restrict__ ewA, float* __restrict__ ewB,
    float* __restrict__ SpA, float* __restrict__ SpB)
{
    __shared__ float red[4];
    int half = gridDim.x >> 1;
    int side = (blockIdx.x >= half);
    const int* csr = side ? csrPost : csrPre;
    const float* y = side ? yB : yA;
    float Mv = funkey((side ? MkB : MkA)[0]);
    float* ew = side ? ewB : ewA;
    float* Sp = side ? SpB : SpA;
    int b = side ? (blockIdx.x - half) : blockIdx.x;

    int tid = threadIdx.x, lane = tid & 63, wid = tid >> 6;
    int gid = b*256 + tid, stride = half*256;
    float ls = 0.f;
    for (int j = gid; j < E; j += stride){
        float w = expf(y[csr[j]] - Mv);
        ew[j] = w;
        ls += w;
    }
    #pragma unroll
    for (int o = 1; o < 64; o <<= 1) ls += __shfl_xor(ls, o);
    if (lane == 0) red[wid] = ls;
    __syncthreads();
    if (tid == 0) atomicAdd(Sp, red[0] + red[1] + red[2] + red[3]);
}

// ---------------- dual-side CSR gather of fp8 rows + sdeg --------------------
__global__ __launch_bounds__(256) void k_gather2(
    const int* __restrict__ rpPre, const int* __restrict__ csrPre, int T,
    const int* __restrict__ rpPost, const int* __restrict__ csrPost, int P,
    const float* __restrict__ ewA, const float* __restrict__ ewB,
    const uchar_t* __restrict__ XP, const uchar_t* __restrict__ XT,
    ushort_t* __restrict__ GbA, ushort_t* __restrict__ GbB,
    float* __restrict__ sdegA, float* __restrict__ sdegB)
{
    int nbT = (T + 15) >> 4;
    int side = (blockIdx.x >= nbT);
    const int* rp   = side ? rpPost : rpPre;
    const int* csr  = side ? csrPost : csrPre;
    const float* ew = side ? ewB : ewA;
    const uchar_t* X = side ? XT : XP;
    ushort_t* G     = side ? GbB : GbA;
    float* sdeg     = side ? sdegB : sdegA;
    int Nrow        = side ? P : T;
    int b = side ? (blockIdx.x - nbT) : blockIdx.x;

    int tid = threadIdx.x;
    int g = tid >> 4, gl = tid & 15;          // 16 groups x 16 lanes
    int r = b*16 + g;
    if (r >= Nrow) return;
    int j0 = rp[r], j1 = rp[r+1];
    const int2* X8 = (const int2*)X;          // fp8 row = 16 int2 (128 fp8)
    float a[8] = {0.f,0.f,0.f,0.f,0.f,0.f,0.f,0.f};
    float se = 0.f;
    int j = j0;
    for (; j + 1 < j1; j += 2){
        int s0 = csr[j], s1 = csr[j+1];
        float e0 = ew[j], e1 = ew[j+1];
        int2 u0 = X8[(size_t)s0*16 + gl];
        int2 u1 = X8[(size_t)s1*16 + gl];
        se += e0 + e1;
        acc8f8(a, u0, e0);
        acc8f8(a, u1, e1);
    }
    if (j < j1){
        int s0 = csr[j];
        float e0 = ew[j];
        int2 u0 = X8[(size_t)s0*16 + gl];
        se += e0;
        acc8f8(a, u0, e0);
    }
    int4 o;
    o.x = (int)((((unsigned)f2bf(a[1])) << 16) | (unsigned)f2bf(a[0]));
    o.y = (int)((((unsigned)f2bf(a[3])) << 16) | (unsigned)f2bf(a[2]));
    o.z = (int)((((unsigned)f2bf(a[5])) << 16) | (unsigned)f2bf(a[4]));
    o.w = (int)((((unsigned)f2bf(a[7])) << 16) | (unsigned)f2bf(a[6]));
    ((int4*)G)[(size_t)r*16 + gl] = o;
    if (gl == 0) sdeg[r] = se;
}

// ---------------- dual-side update GEMM --------------------------------------
// out = relu(A1 + A1@Wtop + invS*(G@Wc + sdeg*bc) + b)   [IN-PLACE: out == A1]
// blocks [0, gridT): transition update; [gridT, gridT+gridP): place update.
// 3-buffer LDS ring (2-deep prefetch, counted vmcnt, raw s_barrier), XOR-
// swizzled via pre-swizzled global source. Residual A1 via identity-MFMA.
// STORE=false (last layer): no out/fp8 stores; colsum into 32 SHADOW COPIES
// (contention /32, reduced in k_head) — the R6 no-store tail was 2500 blocks
// atomicAdd'ing the same 128 addresses.
template<bool STORE>
__global__ __launch_bounds__(256, 4) void k_up2(
    ushort_t* trans_h, ushort_t* place_h,
    const ushort_t* __restrict__ GbA, const ushort_t* __restrict__ GbB,
    const ushort_t* __restrict__ WTl,
    const float* __restrict__ tub, const float* __restrict__ pub,
    const float* __restrict__ bcA, const float* __restrict__ bcB,
    const float* __restrict__ sc4,          // [MkA,SpA,MkB,SpB]
    const float* __restrict__ sdegA, const float* __restrict__ sdegB,
    uchar_t* __restrict__ XT, uchar_t* __restrict__ XP,
    int T, int P, int gridT, int gridP,
    float* __restrict__ meanTsh, float* __restrict__ meanPsh)
{
    __shared__ __align__(16) char As[3*8192];   // 3 x (A1 4KB | A2 4KB)
    __shared__ float csum[H];
    int side = (blockIdx.x >= gridT);
    ushort_t* A1        = side ? place_h : trans_h;
    const ushort_t* A2  = side ? GbB : GbA;
    const ushort_t* WT  = WTl + (side ? 32768 : 0);
    const float* bias   = side ? pub : tub;
    const float* bcp    = side ? bcB : bcA;
    const float* sdeg   = side ? sdegB : sdegA;
    uchar_t* outF8      = side ? XP : XT;
    int M               = side ? P : T;
    int G               = side ? gridP : gridT;
    int t0              = side ? (blockIdx.x - gridT) : blockIdx.x;
    float* colsum       = side ? meanPsh : meanTsh;
    float invS = 1.f / (side ? sc4[3] : sc4[1]);

    int tid = threadIdx.x;
    int lane = tid & 63, wid = tid >> 6;
    int quad = lane >> 4, l15 = lane & 15;
    int strip = wid*32;
    short8 bfr1[2][4], bfr2[2][4];
    float bcol[2], bc2[2];
    #pragma unroll
    for (int j = 0; j < 2; j++){
        int col = strip + j*16 + l15;
        #pragma unroll
        for (int kk = 0; kk < 4; kk++){
            bfr1[j][kk] = *(const short8*)(WT + (size_t)col*256 + kk*32 + quad*8);
            bfr2[j][kk] = *(const short8*)(WT + (size_t)col*256 + 128 + kk*32 + quad*8);
        }
        bcol[j] = bias[col];
        bc2[j]  = bcp[col];
    }
    // identity B-fragments: transpose the wave's A1 fragment window into C-layout
    short8 If0, If1;
    #pragma unroll
    for (int e = 0; e < 8; e++){
        int kloc = quad*8 + e;
        If0[e] = (kloc == l15)      ? (short)0x3F80 : (short)0;
        If1[e] = (kloc == l15 + 16) ? (short)0x3F80 : (short)0;
    }
    if constexpr (!STORE){ if (tid < H) csum[tid] = 0.f; }
    float cs[2] = {0.f, 0.f};

    int tiles = (M + 15) >> 4;
    if (t0 >= tiles) return;
    int srow = tid >> 4;
    int su = (tid & 15) ^ srow;
    const ushort_t* g1b = A1 + (size_t)srow*H + su*8;
    const ushort_t* g2b = A2 + (size_t)srow*H + su*8;
    char* AsB = As;

    #define STAGE_UP(bo, t) do { \
        gll16(g1b + (size_t)(t)*(16*H), AsB + (bo) + (wid<<10)); \
        gll16(g2b + (size_t)(t)*(16*H), AsB + (bo) + 4096 + (wid<<10)); \
    } while(0)

    STAGE_UP(0, t0);
    int t1p = t0 + G;
    if (t1p < tiles){
        STAGE_UP(8192, t1p);
        asm volatile("s_waitcnt vmcnt(2)\ns_barrier" ::: "memory");
    } else {
        asm volatile("s_waitcnt vmcnt(0)\ns_barrier" ::: "memory");
    }

    int t = t0, bo = 0;
    for (;;){
        const char* rb = AsB + bo;
        int row0 = t << 4;
        float4 sd4 = *(const float4*)(sdeg + row0 + quad*4);
        float sdv[4] = {sd4.x, sd4.y, sd4.z, sd4.w};
        short8 a1f[4], a2f[4];
        #pragma unroll
        for (int kk = 0; kk < 4; kk++){
            int sw = ((((kk<<2)+quad) ^ l15) << 4);
            a1f[kk] = *(const short8*)(rb + (l15<<8) + sw);
            a2f[kk] = *(const short8*)(rb + 4096 + (l15<<8) + sw);
        }
        short8 ares = *(const short8*)(rb + (l15<<8) + ((((wid<<2)+quad) ^ l15) << 4));
        floatx4 acc1[2], acc2[2];
        acc1[0] = __builtin_amdgcn_mfma_f32_16x16x32_bf16(ares, If0, (floatx4)0.f, 0,0,0);
        acc1[1] = __builtin_amdgcn_mfma_f32_16x16x32_bf16(ares, If1, (floatx4)0.f, 0,0,0);
        acc2[0] = (floatx4)0.f; acc2[1] = (floatx4)0.f;
        #pragma unroll
        for (int j = 0; j < 2; j++){
            #pragma unroll
            for (int kk = 0; kk < 4; kk++)
                acc1[j] = __builtin_amdgcn_mfma_f32_16x16x32_bf16(a1f[kk], bfr1[j][kk], acc1[j], 0,0,0);
            #pragma unroll
            for (int kk = 0; kk < 4; kk++)
                acc2[j] = __builtin_amdgcn_mfma_f32_16x16x32_bf16(a2f[kk], bfr2[j][kk], acc2[j], 0,0,0);
        }
        #pragma unroll
        for (int j = 0; j < 2; j++){
            int col = strip + j*16 + l15;
            #pragma unroll
            for (int rr = 0; rr < 4; rr++){
                int grow = row0 + quad*4 + rr;
                float v = acc1[j][rr] + invS*(acc2[j][rr] + sdv[rr]*bc2[j]) + bcol[j];
                v = fmaxf(v, 0.f);
                if constexpr (STORE){
                    A1[(size_t)grow*H + col] = f2bf(v);       // 8 ushort stores
                    outF8[(size_t)grow*H + col] = f2fp8(v);   // 8 byte stores
                } else {
                    cs[j] += v;
                }
            }
        }
        int tn = t + G;
        if (tn >= tiles) break;
        int tnn = tn + G;
        int bo2 = bo + 8192; if (bo2 >= 24576) bo2 = 0;
        int bo3 = bo2 + 8192; if (bo3 >= 24576) bo3 = 0;
        // wait for stage(tn): ops newer = 1 sdeg + (16|0) stores (+2 stage)
        if (tnn < tiles){
            STAGE_UP(bo3, tnn);
            if constexpr (STORE) asm volatile("s_waitcnt vmcnt(19)\ns_barrier" ::: "memory");
            else                 asm volatile("s_waitcnt vmcnt(3)\ns_barrier" ::: "memory");
        } else {
            if constexpr (STORE) asm volatile("s_waitcnt vmcnt(17)\ns_barrier" ::: "memory");
            else                 asm volatile("s_waitcnt vmcnt(1)\ns_barrier" ::: "memory");
        }
        t = tn; bo = bo2;
    }
    #undef STAGE_UP
    if constexpr (!STORE){
        #pragma unroll
        for (int j = 0; j < 2; j++){
            float v = cs[j];
            v += __shfl_xor(v, 16); v += __shfl_xor(v, 32);
            if (quad == 0) atomicAdd(&csum[strip + j*16 + l15], v);
        }
        __syncthreads();
        if (tid < H) atomicAdd(&colsum[((blockIdx.x & 31) << 7) + tid], csum[tid]);
    }
}

// ---------------- tiny MLP head (reduces 32 mean shadow copies) --------------
__global__ __launch_bounds__(256) void k_head(
    const float* __restrict__ meanPsh, const float* __restrict__ meanTsh,
    float invP, float invT,
    const float* __restrict__ Wpp, const float* __restrict__ bpp,
    const float* __restrict__ Wtp, const float* __restrict__ btp,
    const float* __restrict__ prefix,
    const float* __restrict__ W1, const float* __restrict__ b1,
    const float* __restrict__ W2, const float* __restrict__ b2,
    float* __restrict__ h2g)
{
    __shared__ float mp[128], mt[128];
    __shared__ float comb[384];
    __shared__ float h1s[256];
    int tid = threadIdx.x;
    if (tid < 128){
        float s = 0.f;
        for (int c = 0; c < 32; c++) s += meanPsh[(c << 7) + tid];
        mp[tid] = s;
    } else {
        int c2 = tid - 128;
        float s = 0.f;
        for (int c = 0; c < 32; c++) s += meanTsh[(c << 7) + c2];
        mt[c2] = s;
    }
    __syncthreads();
    if (tid < 128){
        float a = bpp[tid];
        for (int k = 0; k < 128; k++) a += mp[k]*invP*Wpp[k*H + tid];
        comb[tid] = a;
        comb[256 + tid] = prefix[tid];
    } else {
        int c = tid - 128;
        float a = btp[c];
        for (int k = 0; k < 128; k++) a += mt[k]*invT*Wtp[k*H + c];
        comb[128 + c] = a;
    }
    __syncthreads();
    {
        float a = b1[tid];
        for (int k = 0; k < 384; k++) a += comb[k]*W1[k*256 + tid];
        h1s[tid] = fmaxf(a, 0.f);
    }
    __syncthreads();
    if (tid < 128){
        float a = b2[tid];
        for (int k = 0; k < 256; k++) a += h1s[k]*W2[k*H + tid];
        h2g[tid] = fmaxf(a, 0.f);
    }
}

// ---------------- logits + sigmoid ----------------
__global__ __launch_bounds__(256) void k_logits(
    const float* __restrict__ h2g, const float* __restrict__ W3,
    const float* __restrict__ b3, float* __restrict__ out, int T)
{
    __shared__ float h2l[128];
    int tid = threadIdx.x;
    if (tid < 128) h2l[tid] = h2g[tid];
    __syncthreads();
    int t = blockIdx.x*256 + tid;
    if (t >= T) return;
    float a = b3[t];
    #pragma unroll 8
    for (int k = 0; k < 128; k++) a += h2l[k]*W3[(size_t)k*T + t];
    out[t] = 1.f/(1.f + expf(-a));
}

// ---------------- launch ----------------
extern "C" void kernel_launch(void* const* d_in, const int* in_sizes, int n_in,
                              void* d_out, int out_size, void* d_ws, size_t ws_size,
                              hipStream_t stream)
{
    (void)n_in; (void)out_size; (void)ws_size;
    const float* pf    = (const float*)d_in[0];
    const float* tf    = (const float*)d_in[1];
    const float* pe    = (const float*)d_in[2];
    const int*   pre   = (const int*)d_in[3];
    const int*   post  = (const int*)d_in[4];
    const float* W_pe  = (const float*)d_in[5];
    const float* b_pe  = (const float*)d_in[6];
    const float* W_te  = (const float*)d_in[7];
    const float* b_te  = (const float*)d_in[8];
    const float* W_pr  = (const float*)d_in[9];
    const float* b_pr  = (const float*)d_in[10];
    const float* p2t_W = (const float*)d_in[11];
    const float* p2t_b = (const float*)d_in[12];
    const float* t2p_W = (const float*)d_in[13];
    const float* t2p_b = (const float*)d_in[14];
    const float* pu_W  = (const float*)d_in[15];
    const float* pu_b  = (const float*)d_in[16];
    const float* tu_W  = (const float*)d_in[17];
    const float* tu_b  = (const float*)d_in[18];
    const float* pa_W  = (const float*)d_in[19];
    const float* pa_b  = (const float*)d_in[20];
    const float* ta_W  = (const float*)d_in[21];
    const float* ta_b  = (const float*)d_in[22];
    const float* W_pp  = (const float*)d_in[23];
    const float* b_pp  = (const float*)d_in[24];
    const float* W_tp  = (const float*)d_in[25];
    const float* b_tp  = (const float*)d_in[26];
    const float* W1    = (const float*)d_in[27];
    const float* b1    = (const float*)d_in[28];
    const float* W2    = (const float*)d_in[29];
    const float* b2    = (const float*)d_in[30];
    const float* W3    = (const float*)d_in[31];
    const float* b3    = (const float*)d_in[32];

    int P = in_sizes[0];
    int T = in_sizes[1] / 8;
    int E = in_sizes[3] / 2;
    int plen = in_sizes[2];
    int L = in_sizes[11] / (H*H);

    float* ws = (float*)d_ws;
    size_t fP = (size_t)P*H, fT = (size_t)T*H;
    size_t fN = (fP > fT) ? fP : fT;
    int   Nmax = (P > T) ? P : T;

    float* yA    = ws;                    // [Nmax] place-side scores
    float* yB    = yA + Nmax;             // [Nmax] trans-side scores
    float* sdegA = yB + Nmax;             // [Nmax] per-trans sum of exp
    float* sdegB = sdegA + Nmax;          // [Nmax] per-place sum of exp
    float* sc    = sdegB + Nmax;          // 16 softmax slots
    float* meanPsh = sc + 16;             // [32*128] colsum shadow copies
    float* meanTsh = meanPsh + 4096;      // [32*128]
    float* prefix  = meanTsh + 4096;      // [128]
    float* h2g     = prefix + 128;        // [128]
    float* wvv  = h2g + 128;              // [L*2*128] folded score vectors
    float* c0v  = wvv + (size_t)L*256;    // [32] folded score consts (padded)
    float* bcv  = c0v + 32;               // [L*2*128] folded bias rows

    ushort_t* bh = (ushort_t*)(bcv + (size_t)L*256);
    ushort_t* place_h = bh;               // [P,128] bf16 (updated IN-PLACE)
    ushort_t* trans_h = place_h + fP;     // [T,128] bf16 (updated IN-PLACE)
    ushort_t* GbA     = trans_h + fT;     // [Nmax,128] gathered places (per trans)
    ushort_t* GbB     = GbA + fN;         // [Nmax,128] gathered transes (per place)
    ushort_t* WTb     = GbB + fN;         // L*65536 bf16 combined update weights
    uchar_t*  XP      = (uchar_t*)(WTb + (size_t)L*65536);  // [P,128] fp8 shadow
    uchar_t*  XT      = XP + fP;                             // [T,128] fp8 shadow

    int* iw = (int*)(XT + fT);
    int* cntPre  = iw;                 // [T]
    int* cntPost = cntPre + T;         // [P]
    int* rpPre   = cntPost + P;        // [T+1]
    int* rpPost  = rpPre + (T + 1);    // [P+1]
    int* csrPre  = rpPost + (P + 2);   // [E]
    int* csrPost = csrPre + E;         // [E]
    int* rankPre = csrPost + E;        // [E]
    int* rankPost= rankPre + E;        // [E]
    int* bsumA   = rankPost + E;       // [256]
    int* bsumB   = bsumA + 256;        // [256]

    // edge-weight buffers ALIAS the rank arrays (dead after k_fill2)
    float* ewA = (float*)rankPre;      // [E] edge weights, csrPre order
    float* ewB = (float*)rankPost;     // [E] edge weights, csrPost order

    const int* pre_src  = pre;          const int* pre_dst  = pre + E;
    const int* post_src = post;         const int* post_dst = post + E;

    int wtot = L*32768;
    int nbT = (T + 1023)/1024, nbP = (P + 1023)/1024;

    // update-GEMM grids: ring, 10 tiles/block (halves ramp/drain exposure;
    // all ~1250 fused blocks co-resident, in-flight ~20MB < L2)
    int tilesP = (P + 15) >> 4, tilesT = (T + 15) >> 4;
    int gridP = (tilesP + 9)/10, gridT = (tilesT + 9)/10;
    int nbTg = (T + 15) >> 4, nbPg = (P + 15) >> 4;

    k_init_small<<<1, 128, 0, stream>>>(pe, plen, W_pr, b_pr, prefix,
                                        meanPsh, meanTsh, sc);
    k_wprep2<<<(wtot + 255)/256, 256, 0, stream>>>(p2t_W, t2p_W, tu_W, pu_W, WTb, wtot);
    k_wsmall<<<L*2, 128, 0, stream>>>(p2t_W, t2p_W, tu_W, pu_W, p2t_b, t2p_b,
                                      ta_W, ta_b, pa_W, pa_b, wvv, c0v, bcv);
    k_zero_ints<<<256, 256, 0, stream>>>(iw, P + T);
    k_hist2<<<2048, 256, 0, stream>>>(pre_dst, post_dst, E,
                                      cntPre, cntPost, rankPre, rankPost);
    k_scan_part<<<nbT, 256, 0, stream>>>(cntPre, T, bsumA);
    k_scan_bsum<<<1, 256, 0, stream>>>(bsumA, nbT);
    k_scan_final<<<nbT, 256, 0, stream>>>(cntPre, T, bsumA, rpPre, E);
    k_scan_part<<<nbP, 256, 0, stream>>>(cntPost, P, bsumB);
    k_scan_bsum<<<1, 256, 0, stream>>>(bsumB, nbP);
    k_scan_final<<<nbP, 256, 0, stream>>>(cntPost, P, bsumB, rpPost, E);
    k_fill2<<<1024, 256, 0, stream>>>(pre_src, pre_dst, post_src, post_dst, E,
                                      rpPre, rankPre, csrPre,
                                      rpPost, rankPost, csrPost);

    k_embed_place<<<(P*32 + 255)/256, 256, 0, stream>>>(pf, W_pe, b_pe, place_h, XP, P);
    k_embed_trans<<<(T*32 + 255)/256, 256, 0, stream>>>(tf, W_te, b_te, trans_h, XT, T);

    for (int l = 0; l < L; l++){
        const ushort_t* WTl = WTb + (size_t)l*65536;
        const float* pub  = pu_b  + (size_t)l*H;
        const float* tub  = tu_b  + (size_t)l*H;
        const float* wvA  = wvv + (size_t)(l*2 + 0)*H;
        const float* wvB  = wvv + (size_t)(l*2 + 1)*H;
        const float* bcA  = bcv + (size_t)(l*2 + 0)*H;
        const float* bcB  = bcv + (size_t)(l*2 + 1)*H;
        unsigned* MkA = (unsigned*)(sc + l*4 + 0);   float* SpA = sc + l*4 + 1;
        unsigned* MkB = (unsigned*)(sc + l*4 + 2);   float* SpB = sc + l*4 + 3;
        int last = (l == L-1);

        // scores (both sides) -> edge weights + denominators -> gathers
        k_gemv2<<<1024, 256, 0, stream>>>(place_h, P, trans_h, T, wvA, wvB,
                                          c0v, l*2 + 0, l*2 + 1, yA, yB, MkA, MkB);
        k_ew2<<<1024, 256, 0, stream>>>(csrPre, csrPost, E, yA, yB, MkA, MkB,
                                        ewA, ewB, SpA, SpB);
        k_gather2<<<nbTg + nbPg, 256, 0, stream>>>(rpPre, csrPre, T,
                                                   rpPost, csrPost, P,
                                                   ewA, ewB, XP, XT,
                                                   GbA, GbB, sdegA, sdegB);
        // fused in-place updates (both sides)
        if (last)
            k_up2<false><<<gridT + gridP, 256, 0, stream>>>(
                trans_h, place_h, GbA, GbB, WTl, tub, pub, bcA, bcB,
                sc + l*4, sdegA, sdegB, XT, XP, T, P, gridT, gridP,
                meanTsh, meanPsh);
        else
            k_up2<true><<<gridT + gridP, 256, 0, stream>>>(
                trans_h, place_h, GbA, GbB, WTl, tub, pub, bcA, bcB,
                sc + l*4, sdegA, sdegB, XT, XP, T, P, gridT, gridP,
                meanTsh, meanPsh);
    }

    k_head<<<1, 256, 0, stream>>>(meanPsh, meanTsh, 1.f/(float)P, 1.f/(float)T,
                                  W_pp, b_pp, W_tp, b_tp, prefix, W1, b1, W2, b2, h2g);
    k_logits<<<(T + 255)/256, 256, 0, stream>>>(h2g, W3, b3, (float*)d_out, T);
}